// Round 19
// baseline (106.757 us; speedup 1.0000x reference)
//
#include <hip/hip_runtime.h>
#include <hip/hip_bf16.h>
#include <math.h>

#define TOKS 4096
#define NSEQ 2048
#define NH 16
#define DH 64
#define FD 1024

typedef __bf16 bf16_t;
typedef bf16_t bf16x4 __attribute__((ext_vector_type(4)));
typedef bf16_t bf16x8 __attribute__((ext_vector_type(8)));
typedef float f32x4 __attribute__((ext_vector_type(4)));

// async global->LDS, 16B per lane; LDS dest = wave-uniform base + lane*16
#define GLL16(gsrc, ldst)                                                        \
    __builtin_amdgcn_global_load_lds(                                            \
        (const __attribute__((address_space(1))) void*)(const void*)(gsrc),      \
        (__attribute__((address_space(3))) void*)(void*)(ldst), 16, 0, 0)

__device__ __forceinline__ float geluf(float x) {
    return 0.5f * x * (1.0f + erff(x * 0.70710678118654752f));
}

// Schraudolph-style fast exp2: fma + int-cvt; max rel err ~3.5%.
__device__ __forceinline__ float fexp2(float x) {
    int i = (int)__builtin_fmaf(x, 8388608.0f, 1065063216.0f);
    return __int_as_float(i);
}

// fast gelu: x * sigmoid(1.702 x); sigmoid via fexp2 + hw rcp.
__device__ __forceinline__ float fgelu(float x) {
    float e = fexp2(-2.4554542f * x);          // e^{-1.702x}
    return x * __builtin_amdgcn_rcpf(1.0f + e);
}

// scalar swizzled address into a [64][64] bf16 tile (chunk-XOR swizzle)
__device__ __forceinline__ int lds_sw(int row, int d) {
    return row * 64 + ((((d >> 3) ^ (row & 7)) & 7) << 3) + (d & 7);
}

// fragment permutation: j = cb*16 + g*4 + r  ->  (cb>>1)*32 + g*8 + (cb&1)*4 + r
__device__ __forceinline__ int vperm(int j) {
    return (j & 32) | ((j & 12) << 1) | ((j & 16) >> 2) | (j & 3);
}

// ================= K0: fused weight prep =================
__global__ __launch_bounds__(256) void k_prep(
    const float* __restrict__ wm, const float* __restrict__ w1, const float* __restrict__ w2,
    const float* __restrict__ wq, const float* __restrict__ wk,
    const float* __restrict__ wv, const float* __restrict__ wo,
    bf16_t* __restrict__ wt, bf16_t* __restrict__ w1t, bf16_t* __restrict__ w2t,
    bf16_t* __restrict__ wqt, bf16_t* __restrict__ wkt,
    bf16_t* __restrict__ wvt, bf16_t* __restrict__ wot)
{
    __shared__ bf16_t t[64 * 65];
    const int b = blockIdx.x;
    const int tid = threadIdx.x;
    if (b < 256) {                 // wm [k][n] -> wt [n][k]
        const int k0 = (b & 15) * 64, n0 = (b >> 4) * 64;
        #pragma unroll
        for (int it = 0; it < 16; it++) {
            int idx = it * 256 + tid;
            int kk = idx >> 6, nn = idx & 63;
            t[nn * 65 + kk] = (bf16_t)wm[(size_t)(k0 + kk) * FD + n0 + nn];
        }
        __syncthreads();
        #pragma unroll
        for (int it = 0; it < 16; it++) {
            int idx = it * 256 + tid;
            int nn = idx >> 6, kk = idx & 63;
            wt[(size_t)(n0 + nn) * FD + k0 + kk] = t[nn * 65 + kk];
        }
    } else if (b < 320) {          // w1 -> w1t image [h][n=256][k-slot perm + swz]
        const int lb = b - 256;
        const int h = lb >> 2, n0 = (lb & 3) * 64;
        const float* src = w1 + (size_t)h * 64 * 256;
        #pragma unroll
        for (int it = 0; it < 16; it++) {
            int idx = it * 256 + tid;
            int kk = idx >> 6, nn = idx & 63;
            t[nn * 65 + kk] = (bf16_t)src[kk * 256 + n0 + nn];
        }
        __syncthreads();
        bf16_t* dst = w1t + (size_t)h * 16384;
        #pragma unroll
        for (int it = 0; it < 16; it++) {
            int idx = it * 256 + tid;
            int nn = idx >> 6, kpos = idx & 63;
            int kb = kpos >> 5, gg = (kpos >> 3) & 3, e = kpos & 7;
            int f = (kb * 2 + (e >> 2)) * 16 + gg * 4 + (e & 3);
            int row = n0 + nn;
            dst[row * 64 + ((((kpos >> 3) ^ (row & 7)) & 7) << 3) + (kpos & 7)] =
                t[nn * 65 + f];
        }
    } else if (b < 384) {          // w2 [h][256][64] -> w2t image [h][n=64][k'=256 swz]
        const int lb = b - 320;
        const int h = lb >> 2, k0 = (lb & 3) * 64;
        const float* src = w2 + (size_t)h * 256 * 64;
        #pragma unroll
        for (int it = 0; it < 16; it++) {
            int idx = it * 256 + tid;
            int kk = idx >> 6, nn = idx & 63;
            t[nn * 65 + kk] = (bf16_t)src[(k0 + kk) * 64 + nn];
        }
        __syncthreads();
        bf16_t* dst = w2t + (size_t)h * 16384;
        #pragma unroll
        for (int it = 0; it < 16; it++) {
            int idx = it * 256 + tid;
            int nn = idx >> 6, kk = idx & 63;
            int c = k0 + vperm(kk);
            int chunk = c >> 3;
            int chunkp = (chunk & 24) | ((chunk ^ nn) & 7);
            dst[nn * 256 + (chunkp << 3) + (c & 7)] = t[nn * 65 + kk];
        }
    } else {                       // wq/wk/wv plain [h][g][f]; wo -> swizzled image
        const int h = b - 384;
        const float* srcs[4] = {wq + h * 4096, wk + h * 4096, wv + h * 4096, wo + h * 4096};
        bf16_t* dsts[4] = {wqt + h * 4096, wkt + h * 4096, wvt + h * 4096, wot + h * 4096};
        #pragma unroll
        for (int m = 0; m < 4; m++) {
            __syncthreads();
            #pragma unroll
            for (int it = 0; it < 16; it++) {
                int idx = it * 256 + tid;
                int ff = idx >> 6, gg = idx & 63;
                t[gg * 65 + ff] = (bf16_t)srcs[m][ff * 64 + gg];
            }
            __syncthreads();
            #pragma unroll
            for (int it = 0; it < 16; it++) {
                int idx = it * 256 + tid;
                int gg = idx >> 6, ff = idx & 63;
                if (m == 3)
                    dsts[m][gg * 64 + ((((ff >> 3) ^ (gg & 7)) & 7) << 3) + (ff & 7)] =
                        t[gg * 65 + ff];
                else
                    dsts[m][gg * 64 + ff] = t[gg * 65 + ff];
            }
        }
    }
}

// ================= K1: LN1 + QKV projections (bf16 MFMA) =================
__global__ __launch_bounds__(256) void k_ln1_qkv(
    const float* __restrict__ x, const float* __restrict__ g1, const float* __restrict__ be1,
    const bf16_t* __restrict__ wqt, const float* __restrict__ bq,
    const bf16_t* __restrict__ wkt, const float* __restrict__ bk,
    const bf16_t* __restrict__ wvt, const float* __restrict__ bv,
    bf16_t* __restrict__ q, bf16_t* __restrict__ k, bf16_t* __restrict__ vt)
{
    __shared__ __align__(16) bf16_t h1s[64 * 64];
    __shared__ __align__(16) bf16_t vts[64 * 72];
    const int h  = blockIdx.y;
    const int t0 = blockIdx.x * 64;
    const int tid = threadIdx.x;

    {
        const int i = tid >> 2, s = tid & 3;
        const float* xr = x + (size_t)(t0 + i) * FD + h * DH + s * 16;
        float vals[16];
        #pragma unroll
        for (int r = 0; r < 4; r++) {
            float4 tmp = *(const float4*)(xr + r * 4);
            vals[r*4+0]=tmp.x; vals[r*4+1]=tmp.y; vals[r*4+2]=tmp.z; vals[r*4+3]=tmp.w;
        }
        float sm = 0.f;
        #pragma unroll
        for (int r = 0; r < 16; r++) sm += vals[r];
        sm += __shfl_xor(sm, 1); sm += __shfl_xor(sm, 2);
        const float mean = sm * (1.0f / 64.0f);
        float vr = 0.f;
        #pragma unroll
        for (int r = 0; r < 16; r++) { float d = vals[r] - mean; vr += d * d; }
        vr += __shfl_xor(vr, 1); vr += __shfl_xor(vr, 2);
        const float rstd = rsqrtf(vr * (1.0f / 64.0f) + 1e-5f);
        bf16x8 o0, o1;
        #pragma unroll
        for (int r = 0; r < 8; r++) {
            int d0 = s * 16 + r, d1 = s * 16 + 8 + r;
            o0[r] = (bf16_t)((vals[r]     - mean) * rstd * g1[d0] + be1[d0]);
            o1[r] = (bf16_t)((vals[8 + r] - mean) * rstd * g1[d1] + be1[d1]);
        }
        *(bf16x8*)&h1s[i * 64 + (((s * 2 + 0) ^ (i & 7)) << 3)] = o0;
        *(bf16x8*)&h1s[i * 64 + (((s * 2 + 1) ^ (i & 7)) << 3)] = o1;
    }
    __syncthreads();

    const int wid = tid >> 6, lane = tid & 63;
    const int g = lane >> 4, c0 = lane & 15;
    const int arow = wid * 16 + c0;

    bf16x8 af0 = *(const bf16x8*)&h1s[arow * 64 + (((g    ) ^ (arow & 7)) << 3)];
    bf16x8 af1 = *(const bf16x8*)&h1s[arow * 64 + (((4 + g) ^ (arow & 7)) << 3)];

    const bf16_t* wqh = wqt + h * 4096;
    const bf16_t* wkh = wkt + h * 4096;
    const bf16_t* wvh = wvt + h * 4096;
    f32x4 aq[4], ak[4], av[4];
    #pragma unroll
    for (int ni = 0; ni < 4; ni++) {
        aq[ni] = (f32x4){0.f, 0.f, 0.f, 0.f};
        ak[ni] = (f32x4){0.f, 0.f, 0.f, 0.f};
        av[ni] = (f32x4){0.f, 0.f, 0.f, 0.f};
    }
    #pragma unroll
    for (int ni = 0; ni < 4; ni++) {
        const int col = ni * 16 + c0;
        bf16x8 b0, b1;
        b0 = *(const bf16x8*)(wqh + col * 64 + g * 8);
        b1 = *(const bf16x8*)(wqh + col * 64 + g * 8 + 32);
        aq[ni] = __builtin_amdgcn_mfma_f32_16x16x32_bf16(af0, b0, aq[ni], 0, 0, 0);
        aq[ni] = __builtin_amdgcn_mfma_f32_16x16x32_bf16(af1, b1, aq[ni], 0, 0, 0);
        b0 = *(const bf16x8*)(wkh + col * 64 + g * 8);
        b1 = *(const bf16x8*)(wkh + col * 64 + g * 8 + 32);
        ak[ni] = __builtin_amdgcn_mfma_f32_16x16x32_bf16(af0, b0, ak[ni], 0, 0, 0);
        ak[ni] = __builtin_amdgcn_mfma_f32_16x16x32_bf16(af1, b1, ak[ni], 0, 0, 0);
        b0 = *(const bf16x8*)(wvh + col * 64 + g * 8);
        b1 = *(const bf16x8*)(wvh + col * 64 + g * 8 + 32);
        av[ni] = __builtin_amdgcn_mfma_f32_16x16x32_bf16(af0, b0, av[ni], 0, 0, 0);
        av[ni] = __builtin_amdgcn_mfma_f32_16x16x32_bf16(af1, b1, av[ni], 0, 0, 0);
    }

    const int rowb = wid * 16 + g * 4;
    const int b = t0 >> 11, n0 = t0 & (NSEQ - 1);
    const size_t qkbase = ((size_t)(b * NH + h) * NSEQ + n0) * DH;

    #pragma unroll
    for (int ni = 0; ni < 4; ni++) {
        const int col = ni * 16 + c0;
        const float bb = bv[h * 64 + col];
        #pragma unroll
        for (int r = 0; r < 4; r++) {
            int i = rowb + r;
            vts[col * 72 + vperm(i)] = (bf16_t)(av[ni][r] + bb);
        }
    }
    __syncthreads();

    #pragma unroll
    for (int ni = 0; ni < 4; ni++) {
        const int col = ni * 16 + c0;
        const float bb = bq[h * 64 + col];
        #pragma unroll
        for (int r = 0; r < 4; r++)
            h1s[lds_sw(rowb + r, col)] = (bf16_t)((aq[ni][r] + bb) * 0.045084220f);
    }
    __syncthreads();
    {
        const int row = tid >> 2, cp = (tid & 3) * 2;
        *(bf16x8*)(q + qkbase + row * DH + cp * 8) =
            *(const bf16x8*)&h1s[row * 64 + ((cp ^ (row & 7)) << 3)];
        *(bf16x8*)(q + qkbase + row * DH + (cp + 1) * 8) =
            *(const bf16x8*)&h1s[row * 64 + (((cp + 1) ^ (row & 7)) << 3)];
        const int d = tid >> 2, c16 = tid & 3;
        size_t vbase = ((size_t)(b * NH + h) * DH + d) * NSEQ + n0 + c16 * 16;
        *(bf16x8*)(vt + vbase)     = *(const bf16x8*)&vts[d * 72 + c16 * 16];
        *(bf16x8*)(vt + vbase + 8) = *(const bf16x8*)&vts[d * 72 + c16 * 16 + 8];
    }
    __syncthreads();

    #pragma unroll
    for (int ni = 0; ni < 4; ni++) {
        const int col = ni * 16 + c0;
        const float bb = bk[h * 64 + col];
        #pragma unroll
        for (int r = 0; r < 4; r++)
            h1s[lds_sw(rowb + r, col)] = (bf16_t)(ak[ni][r] + bb);
    }
    __syncthreads();
    {
        const int row = tid >> 2, cp = (tid & 3) * 2;
        *(bf16x8*)(k + qkbase + row * DH + cp * 8) =
            *(const bf16x8*)&h1s[row * 64 + ((cp ^ (row & 7)) << 3)];
        *(bf16x8*)(k + qkbase + row * DH + (cp + 1) * 8) =
            *(const bf16x8*)&h1s[row * 64 + (((cp + 1) ^ (row & 7)) << 3)];
    }
}

// ================= K2: bf16 MFMA flash attention =================
// Plain launch_bounds: VGPR 48 / LDS 32KB allow a 5th block per CU so the
// scheduler can rebalance the tail (hard 4-block cap showed 32% occupancy).
__global__ __launch_bounds__(256) void k_attn(
    const bf16_t* __restrict__ qg, const bf16_t* __restrict__ kg,
    const bf16_t* __restrict__ vt, bf16_t* __restrict__ attnb)
{
    __shared__ __align__(16) bf16_t Ks[2][4096];
    __shared__ __align__(16) bf16_t Vs[2][4096];

    const int bx = blockIdx.x;
    const int bh = ((bx & 7) << 2) | ((bx >> 3) & 3);
    const int qb = blockIdx.y;
    const int tid = threadIdx.x;
    const int wid = tid >> 6, lane = tid & 63;
    const int g = lane >> 4, c0 = lane & 15;
    const int prow = wid * 16 + c0;

    bf16x8 aqf[2];
    {
        const int qrow = qb * 64 + prow;
        const bf16_t* qp = qg + ((size_t)bh * NSEQ + qrow) * DH + g * 8;
        aqf[0] = *(const bf16x8*)qp;
        aqf[1] = *(const bf16x8*)(qp + 32);
    }
    bf16x8 ones;
    #pragma unroll
    for (int e = 0; e < 8; e++) ones[e] = (bf16_t)1.0f;

    int soff[4][2];
    #pragma unroll
    for (int cb = 0; cb < 4; cb++)
        #pragma unroll
        for (int kb = 0; kb < 2; kb++) {
            int row = cb * 16 + c0;
            soff[cb][kb] = row * 64 + (((g + (kb << 2)) ^ (row & 7)) << 3);
        }

    const bf16_t* kbase = kg + (size_t)bh * NSEQ * DH;
    const bf16_t* vbase = vt + (size_t)bh * DH * NSEQ;
    const int gA = wid * 2, gB = gA + 1;
    const int lcA = gA * 64 + lane, lcB = gB * 64 + lane;
    const int rowA = lcA >> 3, ccA = (lcA & 7) ^ (rowA & 7);
    const int rowB = lcB >> 3, ccB = (lcB & 7) ^ (rowB & 7);
    const bf16_t* kpA = kbase + rowA * DH + ccA * 8;
    const bf16_t* kpB = kbase + rowB * DH + ccB * 8;
    const bf16_t* vpA = vbase + (size_t)rowA * NSEQ + ccA * 8;
    const bf16_t* vpB = vbase + (size_t)rowB * NSEQ + ccB * 8;

    GLL16(kpA, (char*)&Ks[0][0] + (gA << 10));
    GLL16(kpB, (char*)&Ks[0][0] + (gB << 10));
    GLL16(vpA, (char*)&Vs[0][0] + (gA << 10));
    GLL16(vpB, (char*)&Vs[0][0] + (gB << 10));
    kpA += 64 * DH; kpB += 64 * DH; vpA += 64; vpB += 64;

    f32x4 O[4];
    #pragma unroll
    for (int cb = 0; cb < 4; cb++) O[cb] = (f32x4){0.f, 0.f, 0.f, 0.f};
    f32x4 l_acc = (f32x4){0.f, 0.f, 0.f, 0.f};

    auto tile = [&](const bf16_t* Kc, const bf16_t* Vc,
                    bf16_t* Kn, bf16_t* Vn, bool pref) {
        __syncthreads();
        if (pref) {
            GLL16(kpA, (char*)Kn + (gA << 10));
            GLL16(kpB, (char*)Kn + (gB << 10));
            GLL16(vpA, (char*)Vn + (gA << 10));
            GLL16(vpB, (char*)Vn + (gB << 10));
            kpA += 64 * DH; kpB += 64 * DH; vpA += 64; vpB += 64;
        }

        f32x4 S[4];
        #pragma unroll
        for (int cb = 0; cb < 4; cb++) {
            f32x4 acc = (f32x4){0.f, 0.f, 0.f, 0.f};
            acc = __builtin_amdgcn_mfma_f32_16x16x32_bf16(
                *(const bf16x8*)&Kc[soff[cb][0]], aqf[0], acc, 0, 0, 0);
            acc = __builtin_amdgcn_mfma_f32_16x16x32_bf16(
                *(const bf16x8*)&Kc[soff[cb][1]], aqf[1], acc, 0, 0, 0);
            S[cb] = acc;
        }

        bf16x8 pa0, pa1;
        #pragma unroll
        for (int cb = 0; cb < 2; cb++)
            #pragma unroll
            for (int r = 0; r < 4; r++)
                pa0[cb * 4 + r] = (bf16_t)fexp2(S[cb][r]);
        #pragma unroll
        for (int cb = 0; cb < 2; cb++)
            #pragma unroll
            for (int r = 0; r < 4; r++)
                pa1[cb * 4 + r] = (bf16_t)fexp2(S[2 + cb][r]);

        l_acc = __builtin_amdgcn_mfma_f32_16x16x32_bf16(ones, pa0, l_acc, 0, 0, 0);
        l_acc = __builtin_amdgcn_mfma_f32_16x16x32_bf16(ones, pa1, l_acc, 0, 0, 0);

        #pragma unroll
        for (int cb = 0; cb < 4; cb++) {
            f32x4 acc = O[cb];
            acc = __builtin_amdgcn_mfma_f32_16x16x32_bf16(
                *(const bf16x8*)&Vc[soff[cb][0]], pa0, acc, 0, 0, 0);
            acc = __builtin_amdgcn_mfma_f32_16x16x32_bf16(
                *(const bf16x8*)&Vc[soff[cb][1]], pa1, acc, 0, 0, 0);
            O[cb] = acc;
        }
    };

    #pragma unroll 1
    for (int kt2 = 0; kt2 < 16; kt2++) {
        tile(Ks[0], Vs[0], Ks[1], Vs[1], true);
        tile(Ks[1], Vs[1], Ks[0], Vs[0], kt2 < 15);
    }

    __syncthreads();
    const float inv = 1.0f / l_acc[0];
    bf16_t* Tb = Ks[0];
    #pragma unroll
    for (int cb = 0; cb < 4; cb++)
        #pragma unroll
        for (int r = 0; r < 4; r++) {
            int d = cb * 16 + g * 4 + r;
            Tb[lds_sw(prow, d)] = (bf16_t)(O[cb][r] * inv);
        }
    __syncthreads();
    {
        const int row = tid >> 2, cp = (tid & 3) * 2;
        size_t gbase = ((size_t)bh * NSEQ + qb * 64 + row) * DH;
        *(bf16x8*)(attnb + gbase + cp * 8) =
            *(const bf16x8*)&Tb[row * 64 + ((cp ^ (row & 7)) << 3)];
        *(bf16x8*)(attnb + gbase + (cp + 1) * 8) =
            *(const bf16x8*)&Tb[row * 64 + (((cp + 1) ^ (row & 7)) << 3)];
    }
}

// ================= K3: fused proj + residual + LN2 + FFN + residual ==============
// Two-phase staging: barrier 1 covers only wos (8 KB); the 64 KB w1/w2 stream
// is issued after it and drains under proj+LN2 (phase-level T14).
__global__ __launch_bounds__(512, 4) void k_pffn(
    const bf16_t* __restrict__ attnb, const bf16_t* __restrict__ wot,
    const float* __restrict__ bo, const float* __restrict__ x,
    const float* __restrict__ g2, const float* __restrict__ be2,
    const bf16_t* __restrict__ w1t, const float* __restrict__ b1,
    const bf16_t* __restrict__ w2t, const float* __restrict__ b2,
    bf16_t* __restrict__ outp)
{
    __shared__ __align__(16) bf16_t wos[4096];       // 8 KB  (swizzled image)
    __shared__ __align__(16) bf16_t w1s[16384];      // 32 KB (perm+swz image)
    __shared__ __align__(16) bf16_t w2s[16384];      // 32 KB (swizzled image)
    const int fid = blockIdx.x + 32 * blockIdx.y;
    const int rem = (fid & 7) * 64 + (fid >> 3);
    const int h   = rem >> 5;
    const int t0  = (rem & 31) * 128;
    const int tid = threadIdx.x;
    const int wid = tid >> 6, lane = tid & 63;
    const int g = lane >> 4, c0 = lane & 15;
    const int b = t0 >> 11, n0 = t0 & (NSEQ - 1);
    const int tok = t0 + wid * 16 + c0;

    // T14: issue attn/x/bias loads up front.
    const bf16_t* ah = attnb + ((size_t)(b * NH + h) * NSEQ + n0) * DH;
    bf16x8 paf0 = *(const bf16x8*)(ah + (wid * 16 + c0) * DH + g * 8);
    bf16x8 paf1 = *(const bf16x8*)(ah + (wid * 16 + c0) * DH + g * 8 + 32);
    float4 xr4[4], bo4[4];
    #pragma unroll
    for (int ni = 0; ni < 4; ni++) {
        xr4[ni] = *(const float4*)(x + (size_t)tok * FD + h * DH + ni * 16 + g * 4);
        bo4[ni] = *(const float4*)(bo + h * DH + ni * 16 + g * 4);
    }

    const bf16_t* s1 = w1t + (size_t)h * 16384;
    const bf16_t* s2 = w2t + (size_t)h * 16384;
    { // phase 1: stage wos (8 KB) only, then barrier
        const bf16_t* s0 = wot + h * 4096;
        GLL16(s0 + wid * 512 + lane * 8, (char*)wos + (wid << 10));
        __syncthreads();
    }
    { // phase 2: issue w1/w2 staging (64 KB); it drains under proj+LN2
        #pragma unroll
        for (int i = 0; i < 4; i++) {
            int grp = wid * 4 + i;
            GLL16(s1 + grp * 512 + lane * 8, (char*)w1s + (grp << 10));
            GLL16(s2 + grp * 512 + lane * 8, (char*)w2s + (grp << 10));
        }
    }

    // ---- proj (swapped): lane holds o1[tok][f = ni*16 + g*4 + r] ----
    float o1[4][4];
    #pragma unroll
    for (int ni = 0; ni < 4; ni++) {
        f32x4 acc = (f32x4){0.f, 0.f, 0.f, 0.f};
        const int orow = ni * 16 + c0;
        bf16x8 b0  = *(const bf16x8*)&wos[orow * 64 + (((g    ) ^ (orow & 7)) << 3)];
        bf16x8 b1f = *(const bf16x8*)&wos[orow * 64 + (((4 + g) ^ (orow & 7)) << 3)];
        acc = __builtin_amdgcn_mfma_f32_16x16x32_bf16(b0, paf0, acc, 0, 0, 0);
        acc = __builtin_amdgcn_mfma_f32_16x16x32_bf16(b1f, paf1, acc, 0, 0, 0);
        o1[ni][0] = acc[0] + bo4[ni].x + xr4[ni].x;
        o1[ni][1] = acc[1] + bo4[ni].y + xr4[ni].y;
        o1[ni][2] = acc[2] + bo4[ni].z + xr4[ni].z;
        o1[ni][3] = acc[3] + bo4[ni].w + xr4[ni].w;
    }

    // ---- LN2: in-lane 16-sum + 2 shuffles ----
    float s = 0.f;
    #pragma unroll
    for (int ni = 0; ni < 4; ni++)
        #pragma unroll
        for (int r = 0; r < 4; r++) s += o1[ni][r];
    s += __shfl_xor(s, 16);
    s += __shfl_xor(s, 32);
    const float mean = s * (1.0f / 64.0f);
    float v = 0.f;
    #pragma unroll
    for (int ni = 0; ni < 4; ni++)
        #pragma unroll
        for (int r = 0; r < 4; r++) { float d = o1[ni][r] - mean; v += d * d; }
    v += __shfl_xor(v, 16);
    v += __shfl_xor(v, 32);
    const float rstd = rsqrtf(v * (1.0f / 64.0f) + 1e-5f);

    // h2 packed DIRECTLY into GEMM1 B-fragments (w1t k-perm compensates)
    bf16x8 hb0, hb1;
    #pragma unroll
    for (int ni = 0; ni < 4; ni++) {
        const float4 g24 = *(const float4*)(g2 + ni * 16 + g * 4);
        const float4 be4 = *(const float4*)(be2 + ni * 16 + g * 4);
        #pragma unroll
        for (int r = 0; r < 4; r++) {
            float hv = (o1[ni][r] - mean) * rstd * ((const float*)&g24)[r]
                       + ((const float*)&be4)[r];
            if (ni < 2) hb0[(ni & 1) * 4 + r] = (bf16_t)hv;
            else        hb1[(ni & 1) * 4 + r] = (bf16_t)hv;
        }
    }
    __syncthreads();   // barrier 2: w1s/w2s staged (mostly drained already)

    // ---- GEMM1+GEMM2 interleaved per-ub ----
    const float* b1h = b1 + h * 256;
    f32x4 acc2[4];
    #pragma unroll
    for (int nt = 0; nt < 4; nt++) acc2[nt] = (f32x4){0.f, 0.f, 0.f, 0.f};

    #pragma unroll
    for (int ub = 0; ub < 4; ub++) {
        f32x4 a4[4];
        #pragma unroll
        for (int j = 0; j < 4; j++) {
            const int wrow = (ub * 4 + j) * 16 + c0;
            bf16x8 bf0 = *(const bf16x8*)&w1s[wrow * 64 + (((g    ) ^ (wrow & 7)) << 3)];
            bf16x8 bf1 = *(const bf16x8*)&w1s[wrow * 64 + (((4 + g) ^ (wrow & 7)) << 3)];
            f32x4 acc = (f32x4){0.f, 0.f, 0.f, 0.f};
            acc = __builtin_amdgcn_mfma_f32_16x16x32_bf16(bf0, hb0, acc, 0, 0, 0);
            acc = __builtin_amdgcn_mfma_f32_16x16x32_bf16(bf1, hb1, acc, 0, 0, 0);
            a4[j] = acc;
        }
        float4 bb0 = *(const float4*)(b1h + (ub * 4 + 0) * 16 + g * 4);
        float4 bb1 = *(const float4*)(b1h + (ub * 4 + 1) * 16 + g * 4);
        float4 bb2 = *(const float4*)(b1h + (ub * 4 + 2) * 16 + g * 4);
        float4 bb3 = *(const float4*)(b1h + (ub * 4 + 3) * 16 + g * 4);
        bf16x8 p0, p1;
        #pragma unroll
        for (int r = 0; r < 4; r++) {
            p0[r]     = (bf16_t)fgelu(a4[0][r] + ((const float*)&bb0)[r]);
            p0[4 + r] = (bf16_t)fgelu(a4[1][r] + ((const float*)&bb1)[r]);
            p1[r]     = (bf16_t)fgelu(a4[2][r] + ((const float*)&bb2)[r]);
            p1[4 + r] = (bf16_t)fgelu(a4[3][r] + ((const float*)&bb3)[r]);
        }
        #pragma unroll
        for (int nt = 0; nt < 4; nt++) {
            const int vrow = nt * 16 + c0;
            bf16x8 bw0 = *(const bf16x8*)&w2s[vrow * 256 +
                            ((ub * 8 + ((g    ) ^ (vrow & 7))) << 3)];
            bf16x8 bw1 = *(const bf16x8*)&w2s[vrow * 256 +
                            ((ub * 8 + ((g + 4) ^ (vrow & 7))) << 3)];
            acc2[nt] = __builtin_amdgcn_mfma_f32_16x16x32_bf16(bw0, p0, acc2[nt], 0, 0, 0);
            acc2[nt] = __builtin_amdgcn_mfma_f32_16x16x32_bf16(bw1, p1, acc2[nt], 0, 0, 0);
        }
    }

    // ---- epilogue ----
    const float* b2h = b2 + h * 64;
    #pragma unroll
    for (int nt = 0; nt < 4; nt++) {
        const float4 b24 = *(const float4*)(b2h + nt * 16 + g * 4);
        bf16x4 ow;
        ow[0] = (bf16_t)(fgelu(acc2[nt][0] + b24.x) + o1[nt][0]);
        ow[1] = (bf16_t)(fgelu(acc2[nt][1] + b24.y) + o1[nt][1]);
        ow[2] = (bf16_t)(fgelu(acc2[nt][2] + b24.z) + o1[nt][2]);
        ow[3] = (bf16_t)(fgelu(acc2[nt][3] + b24.w) + o1[nt][3]);
        *(bf16x4*)(outp + (size_t)tok * FD + h * DH + nt * 16 + g * 4) = ow;
    }
}

// ================= K5: merge GEMM (bf16 MFMA, gll staging) =================
__global__ __launch_bounds__(256) void k_merge(
    const bf16_t* __restrict__ A, const bf16_t* __restrict__ Wt, const float* __restrict__ bias,
    float* __restrict__ C)
{
    __shared__ __align__(16) bf16_t As[128 * 64];
    __shared__ __align__(16) bf16_t Bs[64 * 64];
    const int n0 = blockIdx.x * 64;
    const int m0 = blockIdx.y * 128;
    const int tid = threadIdx.x;
    const int wid = tid >> 6, lane = tid & 63;
    const int c0 = lane & 15, g = lane >> 4;

    const bf16_t* aS[4]; int aO[4];
    #pragma unroll
    for (int i = 0; i < 4; i++) {
        int grp = wid * 4 + i;
        int lc = grp * 64 + lane;
        int row = lc >> 3, cc = (lc & 7) ^ (row & 7);
        aS[i] = A + (size_t)(m0 + row) * FD + cc * 8;
        aO[i] = grp << 10;
    }
    const bf16_t* bS[2]; int bO[2];
    #pragma unroll
    for (int i = 0; i < 2; i++) {
        int grp = wid * 2 + i;
        int lc = grp * 64 + lane;
        int row = lc >> 3, cc = (lc & 7) ^ (row & 7);
        bS[i] = Wt + (size_t)(n0 + row) * FD + cc * 8;
        bO[i] = grp << 10;
    }

    f32x4 acc[2][4];
    #pragma unroll
    for (int mi = 0; mi < 2; mi++)
        #pragma unroll
        for (int ni = 0; ni < 4; ni++)
            acc[mi][ni] = (f32x4){0.f, 0.f, 0.f, 0.f};

    float bv[4];
    #pragma unroll
    for (int ni = 0; ni < 4; ni++) bv[ni] = bias[n0 + ni * 16 + c0];

    for (int k0 = 0; k0 < FD; k0 += 64) {
        __syncthreads();
        #pragma unroll
        for (int i = 0; i < 4; i++) GLL16(aS[i] + k0, (char*)As + aO[i]);
        #pragma unroll
        for (int i = 0; i < 2; i++) GLL16(bS[i] + k0, (char*)Bs + bO[i]);
        __syncthreads();

        bf16x8 af[2][2];
        #pragma unroll
        for (int mi = 0; mi < 2; mi++)
            #pragma unroll
            for (int kk = 0; kk < 2; kk++) {
                int arow = wid * 32 + mi * 16 + c0;
                int ch = kk * 4 + g;
                af[mi][kk] = *(const bf16x8*)&As[arow * 64 + ((ch ^ (arow & 7)) << 3)];
            }
        bf16x8 bfr[4][2];
        #pragma unroll
        for (int ni = 0; ni < 4; ni++)
            #pragma unroll
            for (int kk = 0; kk < 2; kk++) {
                int brow = ni * 16 + c0;
                int ch = kk * 4 + g;
                bfr[ni][kk] = *(const bf16x8*)&Bs[brow * 64 + ((ch ^ (brow & 7)) << 3)];
            }
        #pragma unroll
        for (int mi = 0; mi < 2; mi++)
            #pragma unroll
            for (int ni = 0; ni < 4; ni++)
                #pragma unroll
                for (int kk = 0; kk < 2; kk++)
                    acc[mi][ni] = __builtin_amdgcn_mfma_f32_16x16x32_bf16(
                        af[mi][kk], bfr[ni][kk], acc[mi][ni], 0, 0, 0);
    }

    #pragma unroll
    for (int mi = 0; mi < 2; mi++)
        #pragma unroll
        for (int r = 0; r < 4; r++) {
            int row = m0 + wid * 32 + mi * 16 + g * 4 + r;
            float* cp = C + (size_t)row * FD + n0;
            #pragma unroll
            for (int ni = 0; ni < 4; ni++)
                cp[ni * 16 + c0] = acc[mi][ni][r] + bv[ni];
        }
}

extern "C" void kernel_launch(void* const* d_in, const int* in_sizes, int n_in,
                              void* d_out, int out_size, void* d_ws, size_t ws_size,
                              hipStream_t stream) {
    const float* x   = (const float*)d_in[0];
    const float* g1  = (const float*)d_in[1];
    const float* be1 = (const float*)d_in[2];
    const float* g2  = (const float*)d_in[3];
    const float* be2 = (const float*)d_in[4];
    const float* wq  = (const float*)d_in[5];
    const float* bq  = (const float*)d_in[6];
    const float* wk  = (const float*)d_in[7];
    const float* bk  = (const float*)d_in[8];
    const float* wv  = (const float*)d_in[9];
    const float* bv  = (const float*)d_in[10];
    const float* wo  = (const float*)d_in[11];
    const float* bo  = (const float*)d_in[12];
    const float* w1  = (const float*)d_in[13];
    const float* b1  = (const float*)d_in[14];
    const float* w2  = (const float*)d_in[15];
    const float* b2  = (const float*)d_in[16];
    const float* wm  = (const float*)d_in[17];
    const float* bm  = (const float*)d_in[18];

    char* wsb = (char*)d_ws;
    bf16_t* qb_   = (bf16_t*)(wsb);                        // 8 MB
    bf16_t* kb_   = (bf16_t*)(wsb + (size_t)8  * 1048576); // 8 MB
    bf16_t* vtb   = (bf16_t*)(wsb + (size_t)16 * 1048576); // 8 MB
    bf16_t* attnb = (bf16_t*)(wsb + (size_t)24 * 1048576); // 8 MB ([B,H,N,DH] bf16)
    bf16_t* out2  = (bf16_t*)(wsb + (size_t)40 * 1048576); // 8 MB (FFN output, merge input)
    bf16_t* wtb   = (bf16_t*)(wsb + (size_t)56 * 1048576); // 2 MB
    bf16_t* w1tb  = (bf16_t*)(wsb + (size_t)58 * 1048576); // 512 KB
    bf16_t* w2tb  = (bf16_t*)(wsb + (size_t)58 * 1048576 + 524288); // 512 KB
    bf16_t* wqtb  = (bf16_t*)(wsb + (size_t)59 * 1048576);            // 128 KB
    bf16_t* wktb  = (bf16_t*)(wsb + (size_t)59 * 1048576 + 131072);   // 128 KB
    bf16_t* wvtb  = (bf16_t*)(wsb + (size_t)59 * 1048576 + 262144);   // 128 KB
    bf16_t* wotb  = (bf16_t*)(wsb + (size_t)59 * 1048576 + 393216);   // 128 KB

    k_prep<<<dim3(400), 256, 0, stream>>>(wm, w1, w2, wq, wk, wv, wo,
                                          wtb, w1tb, w2tb, wqtb, wktb, wvtb, wotb);
    k_ln1_qkv<<<dim3(TOKS / 64, NH), 256, 0, stream>>>(x, g1, be1, wqtb, bq, wktb, bk, wvtb, bv,
                                                       qb_, kb_, vtb);
    k_attn<<<dim3(32, NSEQ / 64), 256, 0, stream>>>(qb_, kb_, vtb, attnb);
    k_pffn<<<dim3(32, 16), 512, 0, stream>>>(attnb, wotb, bo, x, g2, be2,
                                             w1tb, b1, w2tb, b2, out2);
    k_merge<<<dim3(FD / 64, TOKS / 128), 256, 0, stream>>>(out2, wtb, bm, (float*)d_out);
}

// Round 20
// 103.986 us; speedup vs baseline: 1.0267x; 1.0267x over previous
//
#include <hip/hip_runtime.h>
#include <hip/hip_bf16.h>
#include <math.h>

#define TOKS 4096
#define NSEQ 2048
#define NH 16
#define DH 64
#define FD 1024

typedef __bf16 bf16_t;
typedef bf16_t bf16x4 __attribute__((ext_vector_type(4)));
typedef bf16_t bf16x8 __attribute__((ext_vector_type(8)));
typedef float f32x4 __attribute__((ext_vector_type(4)));

// async global->LDS, 16B per lane; LDS dest = wave-uniform base + lane*16
#define GLL16(gsrc, ldst)                                                        \
    __builtin_amdgcn_global_load_lds(                                            \
        (const __attribute__((address_space(1))) void*)(const void*)(gsrc),      \
        (__attribute__((address_space(3))) void*)(void*)(ldst), 16, 0, 0)

__device__ __forceinline__ float geluf(float x) {
    return 0.5f * x * (1.0f + erff(x * 0.70710678118654752f));
}

// Schraudolph-style fast exp2: fma + int-cvt; max rel err ~3.5%.
__device__ __forceinline__ float fexp2(float x) {
    int i = (int)__builtin_fmaf(x, 8388608.0f, 1065063216.0f);
    return __int_as_float(i);
}

// fast gelu: x * sigmoid(1.702 x); sigmoid via fexp2 + hw rcp.
__device__ __forceinline__ float fgelu(float x) {
    float e = fexp2(-2.4554542f * x);          // e^{-1.702x}
    return x * __builtin_amdgcn_rcpf(1.0f + e);
}

// scalar swizzled address into a [64][64] bf16 tile (chunk-XOR swizzle)
__device__ __forceinline__ int lds_sw(int row, int d) {
    return row * 64 + ((((d >> 3) ^ (row & 7)) & 7) << 3) + (d & 7);
}

// fragment permutation: j = cb*16 + g*4 + r  ->  (cb>>1)*32 + g*8 + (cb&1)*4 + r
__device__ __forceinline__ int vperm(int j) {
    return (j & 32) | ((j & 12) << 1) | ((j & 16) >> 2) | (j & 3);
}

// ================= K0: fused weight prep =================
__global__ __launch_bounds__(256) void k_prep(
    const float* __restrict__ wm, const float* __restrict__ w1, const float* __restrict__ w2,
    const float* __restrict__ wq, const float* __restrict__ wk,
    const float* __restrict__ wv, const float* __restrict__ wo,
    bf16_t* __restrict__ wt, bf16_t* __restrict__ w1t, bf16_t* __restrict__ w2t,
    bf16_t* __restrict__ wqt, bf16_t* __restrict__ wkt,
    bf16_t* __restrict__ wvt, bf16_t* __restrict__ wot)
{
    __shared__ bf16_t t[64 * 65];
    const int b = blockIdx.x;
    const int tid = threadIdx.x;
    if (b < 256) {                 // wm [k][n] -> wt [n][k]
        const int k0 = (b & 15) * 64, n0 = (b >> 4) * 64;
        #pragma unroll
        for (int it = 0; it < 16; it++) {
            int idx = it * 256 + tid;
            int kk = idx >> 6, nn = idx & 63;
            t[nn * 65 + kk] = (bf16_t)wm[(size_t)(k0 + kk) * FD + n0 + nn];
        }
        __syncthreads();
        #pragma unroll
        for (int it = 0; it < 16; it++) {
            int idx = it * 256 + tid;
            int nn = idx >> 6, kk = idx & 63;
            wt[(size_t)(n0 + nn) * FD + k0 + kk] = t[nn * 65 + kk];
        }
    } else if (b < 320) {          // w1 -> w1t image [h][n=256][k-slot perm + swz]
        const int lb = b - 256;
        const int h = lb >> 2, n0 = (lb & 3) * 64;
        const float* src = w1 + (size_t)h * 64 * 256;
        #pragma unroll
        for (int it = 0; it < 16; it++) {
            int idx = it * 256 + tid;
            int kk = idx >> 6, nn = idx & 63;
            t[nn * 65 + kk] = (bf16_t)src[kk * 256 + n0 + nn];
        }
        __syncthreads();
        bf16_t* dst = w1t + (size_t)h * 16384;
        #pragma unroll
        for (int it = 0; it < 16; it++) {
            int idx = it * 256 + tid;
            int nn = idx >> 6, kpos = idx & 63;
            int kb = kpos >> 5, gg = (kpos >> 3) & 3, e = kpos & 7;
            int f = (kb * 2 + (e >> 2)) * 16 + gg * 4 + (e & 3);
            int row = n0 + nn;
            dst[row * 64 + ((((kpos >> 3) ^ (row & 7)) & 7) << 3) + (kpos & 7)] =
                t[nn * 65 + f];
        }
    } else if (b < 384) {          // w2 [h][256][64] -> w2t image [h][n=64][k'=256 swz]
        const int lb = b - 320;
        const int h = lb >> 2, k0 = (lb & 3) * 64;
        const float* src = w2 + (size_t)h * 256 * 64;
        #pragma unroll
        for (int it = 0; it < 16; it++) {
            int idx = it * 256 + tid;
            int kk = idx >> 6, nn = idx & 63;
            t[nn * 65 + kk] = (bf16_t)src[(k0 + kk) * 64 + nn];
        }
        __syncthreads();
        bf16_t* dst = w2t + (size_t)h * 16384;
        #pragma unroll
        for (int it = 0; it < 16; it++) {
            int idx = it * 256 + tid;
            int nn = idx >> 6, kk = idx & 63;
            int c = k0 + vperm(kk);
            int chunk = c >> 3;
            int chunkp = (chunk & 24) | ((chunk ^ nn) & 7);
            dst[nn * 256 + (chunkp << 3) + (c & 7)] = t[nn * 65 + kk];
        }
    } else {                       // wq/wk/wv plain [h][g][f]; wo -> swizzled image
        const int h = b - 384;
        const float* srcs[4] = {wq + h * 4096, wk + h * 4096, wv + h * 4096, wo + h * 4096};
        bf16_t* dsts[4] = {wqt + h * 4096, wkt + h * 4096, wvt + h * 4096, wot + h * 4096};
        #pragma unroll
        for (int m = 0; m < 4; m++) {
            __syncthreads();
            #pragma unroll
            for (int it = 0; it < 16; it++) {
                int idx = it * 256 + tid;
                int ff = idx >> 6, gg = idx & 63;
                t[gg * 65 + ff] = (bf16_t)srcs[m][ff * 64 + gg];
            }
            __syncthreads();
            #pragma unroll
            for (int it = 0; it < 16; it++) {
                int idx = it * 256 + tid;
                int gg = idx >> 6, ff = idx & 63;
                if (m == 3)
                    dsts[m][gg * 64 + ((((ff >> 3) ^ (gg & 7)) & 7) << 3) + (ff & 7)] =
                        t[gg * 65 + ff];
                else
                    dsts[m][gg * 64 + ff] = t[gg * 65 + ff];
            }
        }
    }
}

// ================= K1: LN1 + QKV projections (bf16 MFMA) =================
__global__ __launch_bounds__(256) void k_ln1_qkv(
    const float* __restrict__ x, const float* __restrict__ g1, const float* __restrict__ be1,
    const bf16_t* __restrict__ wqt, const float* __restrict__ bq,
    const bf16_t* __restrict__ wkt, const float* __restrict__ bk,
    const bf16_t* __restrict__ wvt, const float* __restrict__ bv,
    bf16_t* __restrict__ q, bf16_t* __restrict__ k, bf16_t* __restrict__ vt)
{
    __shared__ __align__(16) bf16_t h1s[64 * 64];
    __shared__ __align__(16) bf16_t vts[64 * 72];
    const int h  = blockIdx.y;
    const int t0 = blockIdx.x * 64;
    const int tid = threadIdx.x;

    {
        const int i = tid >> 2, s = tid & 3;
        const float* xr = x + (size_t)(t0 + i) * FD + h * DH + s * 16;
        float vals[16];
        #pragma unroll
        for (int r = 0; r < 4; r++) {
            float4 tmp = *(const float4*)(xr + r * 4);
            vals[r*4+0]=tmp.x; vals[r*4+1]=tmp.y; vals[r*4+2]=tmp.z; vals[r*4+3]=tmp.w;
        }
        float sm = 0.f;
        #pragma unroll
        for (int r = 0; r < 16; r++) sm += vals[r];
        sm += __shfl_xor(sm, 1); sm += __shfl_xor(sm, 2);
        const float mean = sm * (1.0f / 64.0f);
        float vr = 0.f;
        #pragma unroll
        for (int r = 0; r < 16; r++) { float d = vals[r] - mean; vr += d * d; }
        vr += __shfl_xor(vr, 1); vr += __shfl_xor(vr, 2);
        const float rstd = rsqrtf(vr * (1.0f / 64.0f) + 1e-5f);
        bf16x8 o0, o1;
        #pragma unroll
        for (int r = 0; r < 8; r++) {
            int d0 = s * 16 + r, d1 = s * 16 + 8 + r;
            o0[r] = (bf16_t)((vals[r]     - mean) * rstd * g1[d0] + be1[d0]);
            o1[r] = (bf16_t)((vals[8 + r] - mean) * rstd * g1[d1] + be1[d1]);
        }
        *(bf16x8*)&h1s[i * 64 + (((s * 2 + 0) ^ (i & 7)) << 3)] = o0;
        *(bf16x8*)&h1s[i * 64 + (((s * 2 + 1) ^ (i & 7)) << 3)] = o1;
    }
    __syncthreads();

    const int wid = tid >> 6, lane = tid & 63;
    const int g = lane >> 4, c0 = lane & 15;
    const int arow = wid * 16 + c0;

    bf16x8 af0 = *(const bf16x8*)&h1s[arow * 64 + (((g    ) ^ (arow & 7)) << 3)];
    bf16x8 af1 = *(const bf16x8*)&h1s[arow * 64 + (((4 + g) ^ (arow & 7)) << 3)];

    const bf16_t* wqh = wqt + h * 4096;
    const bf16_t* wkh = wkt + h * 4096;
    const bf16_t* wvh = wvt + h * 4096;
    f32x4 aq[4], ak[4], av[4];
    #pragma unroll
    for (int ni = 0; ni < 4; ni++) {
        aq[ni] = (f32x4){0.f, 0.f, 0.f, 0.f};
        ak[ni] = (f32x4){0.f, 0.f, 0.f, 0.f};
        av[ni] = (f32x4){0.f, 0.f, 0.f, 0.f};
    }
    #pragma unroll
    for (int ni = 0; ni < 4; ni++) {
        const int col = ni * 16 + c0;
        bf16x8 b0, b1;
        b0 = *(const bf16x8*)(wqh + col * 64 + g * 8);
        b1 = *(const bf16x8*)(wqh + col * 64 + g * 8 + 32);
        aq[ni] = __builtin_amdgcn_mfma_f32_16x16x32_bf16(af0, b0, aq[ni], 0, 0, 0);
        aq[ni] = __builtin_amdgcn_mfma_f32_16x16x32_bf16(af1, b1, aq[ni], 0, 0, 0);
        b0 = *(const bf16x8*)(wkh + col * 64 + g * 8);
        b1 = *(const bf16x8*)(wkh + col * 64 + g * 8 + 32);
        ak[ni] = __builtin_amdgcn_mfma_f32_16x16x32_bf16(af0, b0, ak[ni], 0, 0, 0);
        ak[ni] = __builtin_amdgcn_mfma_f32_16x16x32_bf16(af1, b1, ak[ni], 0, 0, 0);
        b0 = *(const bf16x8*)(wvh + col * 64 + g * 8);
        b1 = *(const bf16x8*)(wvh + col * 64 + g * 8 + 32);
        av[ni] = __builtin_amdgcn_mfma_f32_16x16x32_bf16(af0, b0, av[ni], 0, 0, 0);
        av[ni] = __builtin_amdgcn_mfma_f32_16x16x32_bf16(af1, b1, av[ni], 0, 0, 0);
    }

    const int rowb = wid * 16 + g * 4;
    const int b = t0 >> 11, n0 = t0 & (NSEQ - 1);
    const size_t qkbase = ((size_t)(b * NH + h) * NSEQ + n0) * DH;

    #pragma unroll
    for (int ni = 0; ni < 4; ni++) {
        const int col = ni * 16 + c0;
        const float bb = bv[h * 64 + col];
        #pragma unroll
        for (int r = 0; r < 4; r++) {
            int i = rowb + r;
            vts[col * 72 + vperm(i)] = (bf16_t)(av[ni][r] + bb);
        }
    }
    __syncthreads();

    #pragma unroll
    for (int ni = 0; ni < 4; ni++) {
        const int col = ni * 16 + c0;
        const float bb = bq[h * 64 + col];
        #pragma unroll
        for (int r = 0; r < 4; r++)
            h1s[lds_sw(rowb + r, col)] = (bf16_t)((aq[ni][r] + bb) * 0.045084220f);
    }
    __syncthreads();
    {
        const int row = tid >> 2, cp = (tid & 3) * 2;
        *(bf16x8*)(q + qkbase + row * DH + cp * 8) =
            *(const bf16x8*)&h1s[row * 64 + ((cp ^ (row & 7)) << 3)];
        *(bf16x8*)(q + qkbase + row * DH + (cp + 1) * 8) =
            *(const bf16x8*)&h1s[row * 64 + (((cp + 1) ^ (row & 7)) << 3)];
        const int d = tid >> 2, c16 = tid & 3;
        size_t vbase = ((size_t)(b * NH + h) * DH + d) * NSEQ + n0 + c16 * 16;
        *(bf16x8*)(vt + vbase)     = *(const bf16x8*)&vts[d * 72 + c16 * 16];
        *(bf16x8*)(vt + vbase + 8) = *(const bf16x8*)&vts[d * 72 + c16 * 16 + 8];
    }
    __syncthreads();

    #pragma unroll
    for (int ni = 0; ni < 4; ni++) {
        const int col = ni * 16 + c0;
        const float bb = bk[h * 64 + col];
        #pragma unroll
        for (int r = 0; r < 4; r++)
            h1s[lds_sw(rowb + r, col)] = (bf16_t)(ak[ni][r] + bb);
    }
    __syncthreads();
    {
        const int row = tid >> 2, cp = (tid & 3) * 2;
        *(bf16x8*)(k + qkbase + row * DH + cp * 8) =
            *(const bf16x8*)&h1s[row * 64 + ((cp ^ (row & 7)) << 3)];
        *(bf16x8*)(k + qkbase + row * DH + (cp + 1) * 8) =
            *(const bf16x8*)&h1s[row * 64 + (((cp + 1) ^ (row & 7)) << 3)];
    }
}

// ================= K2: bf16 MFMA flash attention =================
// Round-18 configuration: launch_bounds(256,4) measured 47.1 us.
__global__ __launch_bounds__(256, 4) void k_attn(
    const bf16_t* __restrict__ qg, const bf16_t* __restrict__ kg,
    const bf16_t* __restrict__ vt, bf16_t* __restrict__ attnb)
{
    __shared__ __align__(16) bf16_t Ks[2][4096];
    __shared__ __align__(16) bf16_t Vs[2][4096];

    const int bx = blockIdx.x;
    const int bh = ((bx & 7) << 2) | ((bx >> 3) & 3);
    const int qb = blockIdx.y;
    const int tid = threadIdx.x;
    const int wid = tid >> 6, lane = tid & 63;
    const int g = lane >> 4, c0 = lane & 15;
    const int prow = wid * 16 + c0;

    bf16x8 aqf[2];
    {
        const int qrow = qb * 64 + prow;
        const bf16_t* qp = qg + ((size_t)bh * NSEQ + qrow) * DH + g * 8;
        aqf[0] = *(const bf16x8*)qp;
        aqf[1] = *(const bf16x8*)(qp + 32);
    }
    bf16x8 ones;
    #pragma unroll
    for (int e = 0; e < 8; e++) ones[e] = (bf16_t)1.0f;

    int soff[4][2];
    #pragma unroll
    for (int cb = 0; cb < 4; cb++)
        #pragma unroll
        for (int kb = 0; kb < 2; kb++) {
            int row = cb * 16 + c0;
            soff[cb][kb] = row * 64 + (((g + (kb << 2)) ^ (row & 7)) << 3);
        }

    const bf16_t* kbase = kg + (size_t)bh * NSEQ * DH;
    const bf16_t* vbase = vt + (size_t)bh * DH * NSEQ;
    const int gA = wid * 2, gB = gA + 1;
    const int lcA = gA * 64 + lane, lcB = gB * 64 + lane;
    const int rowA = lcA >> 3, ccA = (lcA & 7) ^ (rowA & 7);
    const int rowB = lcB >> 3, ccB = (lcB & 7) ^ (rowB & 7);
    const bf16_t* kpA = kbase + rowA * DH + ccA * 8;
    const bf16_t* kpB = kbase + rowB * DH + ccB * 8;
    const bf16_t* vpA = vbase + (size_t)rowA * NSEQ + ccA * 8;
    const bf16_t* vpB = vbase + (size_t)rowB * NSEQ + ccB * 8;

    GLL16(kpA, (char*)&Ks[0][0] + (gA << 10));
    GLL16(kpB, (char*)&Ks[0][0] + (gB << 10));
    GLL16(vpA, (char*)&Vs[0][0] + (gA << 10));
    GLL16(vpB, (char*)&Vs[0][0] + (gB << 10));
    kpA += 64 * DH; kpB += 64 * DH; vpA += 64; vpB += 64;

    f32x4 O[4];
    #pragma unroll
    for (int cb = 0; cb < 4; cb++) O[cb] = (f32x4){0.f, 0.f, 0.f, 0.f};
    f32x4 l_acc = (f32x4){0.f, 0.f, 0.f, 0.f};

    auto tile = [&](const bf16_t* Kc, const bf16_t* Vc,
                    bf16_t* Kn, bf16_t* Vn, bool pref) {
        __syncthreads();
        if (pref) {
            GLL16(kpA, (char*)Kn + (gA << 10));
            GLL16(kpB, (char*)Kn + (gB << 10));
            GLL16(vpA, (char*)Vn + (gA << 10));
            GLL16(vpB, (char*)Vn + (gB << 10));
            kpA += 64 * DH; kpB += 64 * DH; vpA += 64; vpB += 64;
        }

        f32x4 S[4];
        #pragma unroll
        for (int cb = 0; cb < 4; cb++) {
            f32x4 acc = (f32x4){0.f, 0.f, 0.f, 0.f};
            acc = __builtin_amdgcn_mfma_f32_16x16x32_bf16(
                *(const bf16x8*)&Kc[soff[cb][0]], aqf[0], acc, 0, 0, 0);
            acc = __builtin_amdgcn_mfma_f32_16x16x32_bf16(
                *(const bf16x8*)&Kc[soff[cb][1]], aqf[1], acc, 0, 0, 0);
            S[cb] = acc;
        }

        bf16x8 pa0, pa1;
        #pragma unroll
        for (int cb = 0; cb < 2; cb++)
            #pragma unroll
            for (int r = 0; r < 4; r++)
                pa0[cb * 4 + r] = (bf16_t)fexp2(S[cb][r]);
        #pragma unroll
        for (int cb = 0; cb < 2; cb++)
            #pragma unroll
            for (int r = 0; r < 4; r++)
                pa1[cb * 4 + r] = (bf16_t)fexp2(S[2 + cb][r]);

        l_acc = __builtin_amdgcn_mfma_f32_16x16x32_bf16(ones, pa0, l_acc, 0, 0, 0);
        l_acc = __builtin_amdgcn_mfma_f32_16x16x32_bf16(ones, pa1, l_acc, 0, 0, 0);

        #pragma unroll
        for (int cb = 0; cb < 4; cb++) {
            f32x4 acc = O[cb];
            acc = __builtin_amdgcn_mfma_f32_16x16x32_bf16(
                *(const bf16x8*)&Vc[soff[cb][0]], pa0, acc, 0, 0, 0);
            acc = __builtin_amdgcn_mfma_f32_16x16x32_bf16(
                *(const bf16x8*)&Vc[soff[cb][1]], pa1, acc, 0, 0, 0);
            O[cb] = acc;
        }
    };

    #pragma unroll 1
    for (int kt2 = 0; kt2 < 16; kt2++) {
        tile(Ks[0], Vs[0], Ks[1], Vs[1], true);
        tile(Ks[1], Vs[1], Ks[0], Vs[0], kt2 < 15);
    }

    __syncthreads();
    const float inv = 1.0f / l_acc[0];
    bf16_t* Tb = Ks[0];
    #pragma unroll
    for (int cb = 0; cb < 4; cb++)
        #pragma unroll
        for (int r = 0; r < 4; r++) {
            int d = cb * 16 + g * 4 + r;
            Tb[lds_sw(prow, d)] = (bf16_t)(O[cb][r] * inv);
        }
    __syncthreads();
    {
        const int row = tid >> 2, cp = (tid & 3) * 2;
        size_t gbase = ((size_t)bh * NSEQ + qb * 64 + row) * DH;
        *(bf16x8*)(attnb + gbase + cp * 8) =
            *(const bf16x8*)&Tb[row * 64 + ((cp ^ (row & 7)) << 3)];
        *(bf16x8*)(attnb + gbase + (cp + 1) * 8) =
            *(const bf16x8*)&Tb[row * 64 + (((cp + 1) ^ (row & 7)) << 3)];
    }
}

// ================= K3: fused proj + residual + LN2 + FFN + residual ==============
// Two-phase staging: barrier 1 covers only wos (8 KB); the 64 KB w1/w2 stream
// is issued after it and drains under proj+LN2 (phase-level T14).
__global__ __launch_bounds__(512, 4) void k_pffn(
    const bf16_t* __restrict__ attnb, const bf16_t* __restrict__ wot,
    const float* __restrict__ bo, const float* __restrict__ x,
    const float* __restrict__ g2, const float* __restrict__ be2,
    const bf16_t* __restrict__ w1t, const float* __restrict__ b1,
    const bf16_t* __restrict__ w2t, const float* __restrict__ b2,
    bf16_t* __restrict__ outp)
{
    __shared__ __align__(16) bf16_t wos[4096];       // 8 KB  (swizzled image)
    __shared__ __align__(16) bf16_t w1s[16384];      // 32 KB (perm+swz image)
    __shared__ __align__(16) bf16_t w2s[16384];      // 32 KB (swizzled image)
    const int fid = blockIdx.x + 32 * blockIdx.y;
    const int rem = (fid & 7) * 64 + (fid >> 3);
    const int h   = rem >> 5;
    const int t0  = (rem & 31) * 128;
    const int tid = threadIdx.x;
    const int wid = tid >> 6, lane = tid & 63;
    const int g = lane >> 4, c0 = lane & 15;
    const int b = t0 >> 11, n0 = t0 & (NSEQ - 1);
    const int tok = t0 + wid * 16 + c0;

    // T14: issue attn/x/bias loads up front.
    const bf16_t* ah = attnb + ((size_t)(b * NH + h) * NSEQ + n0) * DH;
    bf16x8 paf0 = *(const bf16x8*)(ah + (wid * 16 + c0) * DH + g * 8);
    bf16x8 paf1 = *(const bf16x8*)(ah + (wid * 16 + c0) * DH + g * 8 + 32);
    float4 xr4[4], bo4[4];
    #pragma unroll
    for (int ni = 0; ni < 4; ni++) {
        xr4[ni] = *(const float4*)(x + (size_t)tok * FD + h * DH + ni * 16 + g * 4);
        bo4[ni] = *(const float4*)(bo + h * DH + ni * 16 + g * 4);
    }

    const bf16_t* s1 = w1t + (size_t)h * 16384;
    const bf16_t* s2 = w2t + (size_t)h * 16384;
    { // phase 1: stage wos (8 KB) only, then barrier
        const bf16_t* s0 = wot + h * 4096;
        GLL16(s0 + wid * 512 + lane * 8, (char*)wos + (wid << 10));
        __syncthreads();
    }
    { // phase 2: issue w1/w2 staging (64 KB); it drains under proj+LN2
        #pragma unroll
        for (int i = 0; i < 4; i++) {
            int grp = wid * 4 + i;
            GLL16(s1 + grp * 512 + lane * 8, (char*)w1s + (grp << 10));
            GLL16(s2 + grp * 512 + lane * 8, (char*)w2s + (grp << 10));
        }
    }

    // ---- proj (swapped): lane holds o1[tok][f = ni*16 + g*4 + r] ----
    float o1[4][4];
    #pragma unroll
    for (int ni = 0; ni < 4; ni++) {
        f32x4 acc = (f32x4){0.f, 0.f, 0.f, 0.f};
        const int orow = ni * 16 + c0;
        bf16x8 b0  = *(const bf16x8*)&wos[orow * 64 + (((g    ) ^ (orow & 7)) << 3)];
        bf16x8 b1f = *(const bf16x8*)&wos[orow * 64 + (((4 + g) ^ (orow & 7)) << 3)];
        acc = __builtin_amdgcn_mfma_f32_16x16x32_bf16(b0, paf0, acc, 0, 0, 0);
        acc = __builtin_amdgcn_mfma_f32_16x16x32_bf16(b1f, paf1, acc, 0, 0, 0);
        o1[ni][0] = acc[0] + bo4[ni].x + xr4[ni].x;
        o1[ni][1] = acc[1] + bo4[ni].y + xr4[ni].y;
        o1[ni][2] = acc[2] + bo4[ni].z + xr4[ni].z;
        o1[ni][3] = acc[3] + bo4[ni].w + xr4[ni].w;
    }

    // ---- LN2: in-lane 16-sum + 2 shuffles ----
    float s = 0.f;
    #pragma unroll
    for (int ni = 0; ni < 4; ni++)
        #pragma unroll
        for (int r = 0; r < 4; r++) s += o1[ni][r];
    s += __shfl_xor(s, 16);
    s += __shfl_xor(s, 32);
    const float mean = s * (1.0f / 64.0f);
    float v = 0.f;
    #pragma unroll
    for (int ni = 0; ni < 4; ni++)
        #pragma unroll
        for (int r = 0; r < 4; r++) { float d = o1[ni][r] - mean; v += d * d; }
    v += __shfl_xor(v, 16);
    v += __shfl_xor(v, 32);
    const float rstd = rsqrtf(v * (1.0f / 64.0f) + 1e-5f);

    // h2 packed DIRECTLY into GEMM1 B-fragments (w1t k-perm compensates)
    bf16x8 hb0, hb1;
    #pragma unroll
    for (int ni = 0; ni < 4; ni++) {
        const float4 g24 = *(const float4*)(g2 + ni * 16 + g * 4);
        const float4 be4 = *(const float4*)(be2 + ni * 16 + g * 4);
        #pragma unroll
        for (int r = 0; r < 4; r++) {
            float hv = (o1[ni][r] - mean) * rstd * ((const float*)&g24)[r]
                       + ((const float*)&be4)[r];
            if (ni < 2) hb0[(ni & 1) * 4 + r] = (bf16_t)hv;
            else        hb1[(ni & 1) * 4 + r] = (bf16_t)hv;
        }
    }
    __syncthreads();   // barrier 2: w1s/w2s staged (mostly drained already)

    // ---- GEMM1+GEMM2 interleaved per-ub ----
    const float* b1h = b1 + h * 256;
    f32x4 acc2[4];
    #pragma unroll
    for (int nt = 0; nt < 4; nt++) acc2[nt] = (f32x4){0.f, 0.f, 0.f, 0.f};

    #pragma unroll
    for (int ub = 0; ub < 4; ub++) {
        f32x4 a4[4];
        #pragma unroll
        for (int j = 0; j < 4; j++) {
            const int wrow = (ub * 4 + j) * 16 + c0;
            bf16x8 bf0 = *(const bf16x8*)&w1s[wrow * 64 + (((g    ) ^ (wrow & 7)) << 3)];
            bf16x8 bf1 = *(const bf16x8*)&w1s[wrow * 64 + (((4 + g) ^ (wrow & 7)) << 3)];
            f32x4 acc = (f32x4){0.f, 0.f, 0.f, 0.f};
            acc = __builtin_amdgcn_mfma_f32_16x16x32_bf16(bf0, hb0, acc, 0, 0, 0);
            acc = __builtin_amdgcn_mfma_f32_16x16x32_bf16(bf1, hb1, acc, 0, 0, 0);
            a4[j] = acc;
        }
        float4 bb0 = *(const float4*)(b1h + (ub * 4 + 0) * 16 + g * 4);
        float4 bb1 = *(const float4*)(b1h + (ub * 4 + 1) * 16 + g * 4);
        float4 bb2 = *(const float4*)(b1h + (ub * 4 + 2) * 16 + g * 4);
        float4 bb3 = *(const float4*)(b1h + (ub * 4 + 3) * 16 + g * 4);
        bf16x8 p0, p1;
        #pragma unroll
        for (int r = 0; r < 4; r++) {
            p0[r]     = (bf16_t)fgelu(a4[0][r] + ((const float*)&bb0)[r]);
            p0[4 + r] = (bf16_t)fgelu(a4[1][r] + ((const float*)&bb1)[r]);
            p1[r]     = (bf16_t)fgelu(a4[2][r] + ((const float*)&bb2)[r]);
            p1[4 + r] = (bf16_t)fgelu(a4[3][r] + ((const float*)&bb3)[r]);
        }
        #pragma unroll
        for (int nt = 0; nt < 4; nt++) {
            const int vrow = nt * 16 + c0;
            bf16x8 bw0 = *(const bf16x8*)&w2s[vrow * 256 +
                            ((ub * 8 + ((g    ) ^ (vrow & 7))) << 3)];
            bf16x8 bw1 = *(const bf16x8*)&w2s[vrow * 256 +
                            ((ub * 8 + ((g + 4) ^ (vrow & 7))) << 3)];
            acc2[nt] = __builtin_amdgcn_mfma_f32_16x16x32_bf16(bw0, p0, acc2[nt], 0, 0, 0);
            acc2[nt] = __builtin_amdgcn_mfma_f32_16x16x32_bf16(bw1, p1, acc2[nt], 0, 0, 0);
        }
    }

    // ---- epilogue ----
    const float* b2h = b2 + h * 64;
    #pragma unroll
    for (int nt = 0; nt < 4; nt++) {
        const float4 b24 = *(const float4*)(b2h + nt * 16 + g * 4);
        bf16x4 ow;
        ow[0] = (bf16_t)(fgelu(acc2[nt][0] + b24.x) + o1[nt][0]);
        ow[1] = (bf16_t)(fgelu(acc2[nt][1] + b24.y) + o1[nt][1]);
        ow[2] = (bf16_t)(fgelu(acc2[nt][2] + b24.z) + o1[nt][2]);
        ow[3] = (bf16_t)(fgelu(acc2[nt][3] + b24.w) + o1[nt][3]);
        *(bf16x4*)(outp + (size_t)tok * FD + h * DH + nt * 16 + g * 4) = ow;
    }
}

// ================= K5: merge GEMM (bf16 MFMA, gll staging) =================
__global__ __launch_bounds__(256) void k_merge(
    const bf16_t* __restrict__ A, const bf16_t* __restrict__ Wt, const float* __restrict__ bias,
    float* __restrict__ C)
{
    __shared__ __align__(16) bf16_t As[128 * 64];
    __shared__ __align__(16) bf16_t Bs[64 * 64];
    const int n0 = blockIdx.x * 64;
    const int m0 = blockIdx.y * 128;
    const int tid = threadIdx.x;
    const int wid = tid >> 6, lane = tid & 63;
    const int c0 = lane & 15, g = lane >> 4;

    const bf16_t* aS[4]; int aO[4];
    #pragma unroll
    for (int i = 0; i < 4; i++) {
        int grp = wid * 4 + i;
        int lc = grp * 64 + lane;
        int row = lc >> 3, cc = (lc & 7) ^ (row & 7);
        aS[i] = A + (size_t)(m0 + row) * FD + cc * 8;
        aO[i] = grp << 10;
    }
    const bf16_t* bS[2]; int bO[2];
    #pragma unroll
    for (int i = 0; i < 2; i++) {
        int grp = wid * 2 + i;
        int lc = grp * 64 + lane;
        int row = lc >> 3, cc = (lc & 7) ^ (row & 7);
        bS[i] = Wt + (size_t)(n0 + row) * FD + cc * 8;
        bO[i] = grp << 10;
    }

    f32x4 acc[2][4];
    #pragma unroll
    for (int mi = 0; mi < 2; mi++)
        #pragma unroll
        for (int ni = 0; ni < 4; ni++)
            acc[mi][ni] = (f32x4){0.f, 0.f, 0.f, 0.f};

    float bv[4];
    #pragma unroll
    for (int ni = 0; ni < 4; ni++) bv[ni] = bias[n0 + ni * 16 + c0];

    for (int k0 = 0; k0 < FD; k0 += 64) {
        __syncthreads();
        #pragma unroll
        for (int i = 0; i < 4; i++) GLL16(aS[i] + k0, (char*)As + aO[i]);
        #pragma unroll
        for (int i = 0; i < 2; i++) GLL16(bS[i] + k0, (char*)Bs + bO[i]);
        __syncthreads();

        bf16x8 af[2][2];
        #pragma unroll
        for (int mi = 0; mi < 2; mi++)
            #pragma unroll
            for (int kk = 0; kk < 2; kk++) {
                int arow = wid * 32 + mi * 16 + c0;
                int ch = kk * 4 + g;
                af[mi][kk] = *(const bf16x8*)&As[arow * 64 + ((ch ^ (arow & 7)) << 3)];
            }
        bf16x8 bfr[4][2];
        #pragma unroll
        for (int ni = 0; ni < 4; ni++)
            #pragma unroll
            for (int kk = 0; kk < 2; kk++) {
                int brow = ni * 16 + c0;
                int ch = kk * 4 + g;
                bfr[ni][kk] = *(const bf16x8*)&Bs[brow * 64 + ((ch ^ (brow & 7)) << 3)];
            }
        #pragma unroll
        for (int mi = 0; mi < 2; mi++)
            #pragma unroll
            for (int ni = 0; ni < 4; ni++)
                #pragma unroll
                for (int kk = 0; kk < 2; kk++)
                    acc[mi][ni] = __builtin_amdgcn_mfma_f32_16x16x32_bf16(
                        af[mi][kk], bfr[ni][kk], acc[mi][ni], 0, 0, 0);
    }

    #pragma unroll
    for (int mi = 0; mi < 2; mi++)
        #pragma unroll
        for (int r = 0; r < 4; r++) {
            int row = m0 + wid * 32 + mi * 16 + g * 4 + r;
            float* cp = C + (size_t)row * FD + n0;
            #pragma unroll
            for (int ni = 0; ni < 4; ni++)
                cp[ni * 16 + c0] = acc[mi][ni][r] + bv[ni];
        }
}

extern "C" void kernel_launch(void* const* d_in, const int* in_sizes, int n_in,
                              void* d_out, int out_size, void* d_ws, size_t ws_size,
                              hipStream_t stream) {
    const float* x   = (const float*)d_in[0];
    const float* g1  = (const float*)d_in[1];
    const float* be1 = (const float*)d_in[2];
    const float* g2  = (const float*)d_in[3];
    const float* be2 = (const float*)d_in[4];
    const float* wq  = (const float*)d_in[5];
    const float* bq  = (const float*)d_in[6];
    const float* wk  = (const float*)d_in[7];
    const float* bk  = (const float*)d_in[8];
    const float* wv  = (const float*)d_in[9];
    const float* bv  = (const float*)d_in[10];
    const float* wo  = (const float*)d_in[11];
    const float* bo  = (const float*)d_in[12];
    const float* w1  = (const float*)d_in[13];
    const float* b1  = (const float*)d_in[14];
    const float* w2  = (const float*)d_in[15];
    const float* b2  = (const float*)d_in[16];
    const float* wm  = (const float*)d_in[17];
    const float* bm  = (const float*)d_in[18];

    char* wsb = (char*)d_ws;
    bf16_t* qb_   = (bf16_t*)(wsb);                        // 8 MB
    bf16_t* kb_   = (bf16_t*)(wsb + (size_t)8  * 1048576); // 8 MB
    bf16_t* vtb   = (bf16_t*)(wsb + (size_t)16 * 1048576); // 8 MB
    bf16_t* attnb = (bf16_t*)(wsb + (size_t)24 * 1048576); // 8 MB ([B,H,N,DH] bf16)
    bf16_t* out2  = (bf16_t*)(wsb + (size_t)40 * 1048576); // 8 MB (FFN output, merge input)
    bf16_t* wtb   = (bf16_t*)(wsb + (size_t)56 * 1048576); // 2 MB
    bf16_t* w1tb  = (bf16_t*)(wsb + (size_t)58 * 1048576); // 512 KB
    bf16_t* w2tb  = (bf16_t*)(wsb + (size_t)58 * 1048576 + 524288); // 512 KB
    bf16_t* wqtb  = (bf16_t*)(wsb + (size_t)59 * 1048576);            // 128 KB
    bf16_t* wktb  = (bf16_t*)(wsb + (size_t)59 * 1048576 + 131072);   // 128 KB
    bf16_t* wvtb  = (bf16_t*)(wsb + (size_t)59 * 1048576 + 262144);   // 128 KB
    bf16_t* wotb  = (bf16_t*)(wsb + (size_t)59 * 1048576 + 393216);   // 128 KB

    k_prep<<<dim3(400), 256, 0, stream>>>(wm, w1, w2, wq, wk, wv, wo,
                                          wtb, w1tb, w2tb, wqtb, wktb, wvtb, wotb);
    k_ln1_qkv<<<dim3(TOKS / 64, NH), 256, 0, stream>>>(x, g1, be1, wqtb, bq, wktb, bk, wvtb, bv,
                                                       qb_, kb_, vtb);
    k_attn<<<dim3(32, NSEQ / 64), 256, 0, stream>>>(qb_, kb_, vtb, attnb);
    k_pffn<<<dim3(32, 16), 512, 0, stream>>>(attnb, wotb, bo, x, g2, be2,
                                             w1tb, b1, w2tb, b2, out2);
    k_merge<<<dim3(FD / 64, TOKS / 128), 256, 0, stream>>>(out2, wtb, bm, (float*)d_out);
}

// Round 21
// 100.719 us; speedup vs baseline: 1.0600x; 1.0324x over previous
//
#include <hip/hip_runtime.h>
#include <hip/hip_bf16.h>
#include <math.h>

#define TOKS 4096
#define NSEQ 2048
#define NH 16
#define DH 64
#define FD 1024

typedef __bf16 bf16_t;
typedef bf16_t bf16x4 __attribute__((ext_vector_type(4)));
typedef bf16_t bf16x8 __attribute__((ext_vector_type(8)));
typedef float f32x4 __attribute__((ext_vector_type(4)));

// async global->LDS, 16B per lane; LDS dest = wave-uniform base + lane*16
#define GLL16(gsrc, ldst)                                                        \
    __builtin_amdgcn_global_load_lds(                                            \
        (const __attribute__((address_space(1))) void*)(const void*)(gsrc),      \
        (__attribute__((address_space(3))) void*)(void*)(ldst), 16, 0, 0)

__device__ __forceinline__ float geluf(float x) {
    return 0.5f * x * (1.0f + erff(x * 0.70710678118654752f));
}

// Schraudolph-style fast exp2: fma + int-cvt; max rel err ~3.5%.
__device__ __forceinline__ float fexp2(float x) {
    int i = (int)__builtin_fmaf(x, 8388608.0f, 1065063216.0f);
    return __int_as_float(i);
}

// fast gelu: x * sigmoid(1.702 x); sigmoid via fexp2 + hw rcp.
__device__ __forceinline__ float fgelu(float x) {
    float e = fexp2(-2.4554542f * x);          // e^{-1.702x}
    return x * __builtin_amdgcn_rcpf(1.0f + e);
}

// scalar swizzled address into a [64][64] bf16 tile (chunk-XOR swizzle)
__device__ __forceinline__ int lds_sw(int row, int d) {
    return row * 64 + ((((d >> 3) ^ (row & 7)) & 7) << 3) + (d & 7);
}

// fragment permutation: j = cb*16 + g*4 + r  ->  (cb>>1)*32 + g*8 + (cb&1)*4 + r
__device__ __forceinline__ int vperm(int j) {
    return (j & 32) | ((j & 12) << 1) | ((j & 16) >> 2) | (j & 3);
}

// ================= K0: fused weight prep =================
__global__ __launch_bounds__(256) void k_prep(
    const float* __restrict__ wm, const float* __restrict__ w1, const float* __restrict__ w2,
    const float* __restrict__ wq, const float* __restrict__ wk,
    const float* __restrict__ wv, const float* __restrict__ wo,
    bf16_t* __restrict__ wt, bf16_t* __restrict__ w1t, bf16_t* __restrict__ w2t,
    bf16_t* __restrict__ wqt, bf16_t* __restrict__ wkt,
    bf16_t* __restrict__ wvt, bf16_t* __restrict__ wot)
{
    __shared__ bf16_t t[64 * 65];
    const int b = blockIdx.x;
    const int tid = threadIdx.x;
    if (b < 256) {                 // wm [k][n] -> wt [n][k]
        const int k0 = (b & 15) * 64, n0 = (b >> 4) * 64;
        #pragma unroll
        for (int it = 0; it < 16; it++) {
            int idx = it * 256 + tid;
            int kk = idx >> 6, nn = idx & 63;
            t[nn * 65 + kk] = (bf16_t)wm[(size_t)(k0 + kk) * FD + n0 + nn];
        }
        __syncthreads();
        #pragma unroll
        for (int it = 0; it < 16; it++) {
            int idx = it * 256 + tid;
            int nn = idx >> 6, kk = idx & 63;
            wt[(size_t)(n0 + nn) * FD + k0 + kk] = t[nn * 65 + kk];
        }
    } else if (b < 320) {          // w1 -> w1t image [h][n=256][k-slot perm + swz]
        const int lb = b - 256;
        const int h = lb >> 2, n0 = (lb & 3) * 64;
        const float* src = w1 + (size_t)h * 64 * 256;
        #pragma unroll
        for (int it = 0; it < 16; it++) {
            int idx = it * 256 + tid;
            int kk = idx >> 6, nn = idx & 63;
            t[nn * 65 + kk] = (bf16_t)src[kk * 256 + n0 + nn];
        }
        __syncthreads();
        bf16_t* dst = w1t + (size_t)h * 16384;
        #pragma unroll
        for (int it = 0; it < 16; it++) {
            int idx = it * 256 + tid;
            int nn = idx >> 6, kpos = idx & 63;
            int kb = kpos >> 5, gg = (kpos >> 3) & 3, e = kpos & 7;
            int f = (kb * 2 + (e >> 2)) * 16 + gg * 4 + (e & 3);
            int row = n0 + nn;
            dst[row * 64 + ((((kpos >> 3) ^ (row & 7)) & 7) << 3) + (kpos & 7)] =
                t[nn * 65 + f];
        }
    } else if (b < 384) {          // w2 [h][256][64] -> w2t image [h][n=64][k'=256 swz]
        const int lb = b - 320;
        const int h = lb >> 2, k0 = (lb & 3) * 64;
        const float* src = w2 + (size_t)h * 256 * 64;
        #pragma unroll
        for (int it = 0; it < 16; it++) {
            int idx = it * 256 + tid;
            int kk = idx >> 6, nn = idx & 63;
            t[nn * 65 + kk] = (bf16_t)src[(k0 + kk) * 64 + nn];
        }
        __syncthreads();
        bf16_t* dst = w2t + (size_t)h * 16384;
        #pragma unroll
        for (int it = 0; it < 16; it++) {
            int idx = it * 256 + tid;
            int nn = idx >> 6, kk = idx & 63;
            int c = k0 + vperm(kk);
            int chunk = c >> 3;
            int chunkp = (chunk & 24) | ((chunk ^ nn) & 7);
            dst[nn * 256 + (chunkp << 3) + (c & 7)] = t[nn * 65 + kk];
        }
    } else {                       // wq/wk/wv plain [h][g][f]; wo -> swizzled image
        const int h = b - 384;
        const float* srcs[4] = {wq + h * 4096, wk + h * 4096, wv + h * 4096, wo + h * 4096};
        bf16_t* dsts[4] = {wqt + h * 4096, wkt + h * 4096, wvt + h * 4096, wot + h * 4096};
        #pragma unroll
        for (int m = 0; m < 4; m++) {
            __syncthreads();
            #pragma unroll
            for (int it = 0; it < 16; it++) {
                int idx = it * 256 + tid;
                int ff = idx >> 6, gg = idx & 63;
                t[gg * 65 + ff] = (bf16_t)srcs[m][ff * 64 + gg];
            }
            __syncthreads();
            #pragma unroll
            for (int it = 0; it < 16; it++) {
                int idx = it * 256 + tid;
                int gg = idx >> 6, ff = idx & 63;
                if (m == 3)
                    dsts[m][gg * 64 + ((((ff >> 3) ^ (gg & 7)) & 7) << 3) + (ff & 7)] =
                        t[gg * 65 + ff];
                else
                    dsts[m][gg * 64 + ff] = t[gg * 65 + ff];
            }
        }
    }
}

// ================= K1: LN1 + QKV projections (bf16 MFMA) =================
__global__ __launch_bounds__(256) void k_ln1_qkv(
    const float* __restrict__ x, const float* __restrict__ g1, const float* __restrict__ be1,
    const bf16_t* __restrict__ wqt, const float* __restrict__ bq,
    const bf16_t* __restrict__ wkt, const float* __restrict__ bk,
    const bf16_t* __restrict__ wvt, const float* __restrict__ bv,
    bf16_t* __restrict__ q, bf16_t* __restrict__ k, bf16_t* __restrict__ vt)
{
    __shared__ __align__(16) bf16_t h1s[64 * 64];
    __shared__ __align__(16) bf16_t vts[64 * 72];
    const int h  = blockIdx.y;
    const int t0 = blockIdx.x * 64;
    const int tid = threadIdx.x;

    {
        const int i = tid >> 2, s = tid & 3;
        const float* xr = x + (size_t)(t0 + i) * FD + h * DH + s * 16;
        float vals[16];
        #pragma unroll
        for (int r = 0; r < 4; r++) {
            float4 tmp = *(const float4*)(xr + r * 4);
            vals[r*4+0]=tmp.x; vals[r*4+1]=tmp.y; vals[r*4+2]=tmp.z; vals[r*4+3]=tmp.w;
        }
        float sm = 0.f;
        #pragma unroll
        for (int r = 0; r < 16; r++) sm += vals[r];
        sm += __shfl_xor(sm, 1); sm += __shfl_xor(sm, 2);
        const float mean = sm * (1.0f / 64.0f);
        float vr = 0.f;
        #pragma unroll
        for (int r = 0; r < 16; r++) { float d = vals[r] - mean; vr += d * d; }
        vr += __shfl_xor(vr, 1); vr += __shfl_xor(vr, 2);
        const float rstd = rsqrtf(vr * (1.0f / 64.0f) + 1e-5f);
        bf16x8 o0, o1;
        #pragma unroll
        for (int r = 0; r < 8; r++) {
            int d0 = s * 16 + r, d1 = s * 16 + 8 + r;
            o0[r] = (bf16_t)((vals[r]     - mean) * rstd * g1[d0] + be1[d0]);
            o1[r] = (bf16_t)((vals[8 + r] - mean) * rstd * g1[d1] + be1[d1]);
        }
        *(bf16x8*)&h1s[i * 64 + (((s * 2 + 0) ^ (i & 7)) << 3)] = o0;
        *(bf16x8*)&h1s[i * 64 + (((s * 2 + 1) ^ (i & 7)) << 3)] = o1;
    }
    __syncthreads();

    const int wid = tid >> 6, lane = tid & 63;
    const int g = lane >> 4, c0 = lane & 15;
    const int arow = wid * 16 + c0;

    bf16x8 af0 = *(const bf16x8*)&h1s[arow * 64 + (((g    ) ^ (arow & 7)) << 3)];
    bf16x8 af1 = *(const bf16x8*)&h1s[arow * 64 + (((4 + g) ^ (arow & 7)) << 3)];

    const bf16_t* wqh = wqt + h * 4096;
    const bf16_t* wkh = wkt + h * 4096;
    const bf16_t* wvh = wvt + h * 4096;
    f32x4 aq[4], ak[4], av[4];
    #pragma unroll
    for (int ni = 0; ni < 4; ni++) {
        aq[ni] = (f32x4){0.f, 0.f, 0.f, 0.f};
        ak[ni] = (f32x4){0.f, 0.f, 0.f, 0.f};
        av[ni] = (f32x4){0.f, 0.f, 0.f, 0.f};
    }
    #pragma unroll
    for (int ni = 0; ni < 4; ni++) {
        const int col = ni * 16 + c0;
        bf16x8 b0, b1;
        b0 = *(const bf16x8*)(wqh + col * 64 + g * 8);
        b1 = *(const bf16x8*)(wqh + col * 64 + g * 8 + 32);
        aq[ni] = __builtin_amdgcn_mfma_f32_16x16x32_bf16(af0, b0, aq[ni], 0, 0, 0);
        aq[ni] = __builtin_amdgcn_mfma_f32_16x16x32_bf16(af1, b1, aq[ni], 0, 0, 0);
        b0 = *(const bf16x8*)(wkh + col * 64 + g * 8);
        b1 = *(const bf16x8*)(wkh + col * 64 + g * 8 + 32);
        ak[ni] = __builtin_amdgcn_mfma_f32_16x16x32_bf16(af0, b0, ak[ni], 0, 0, 0);
        ak[ni] = __builtin_amdgcn_mfma_f32_16x16x32_bf16(af1, b1, ak[ni], 0, 0, 0);
        b0 = *(const bf16x8*)(wvh + col * 64 + g * 8);
        b1 = *(const bf16x8*)(wvh + col * 64 + g * 8 + 32);
        av[ni] = __builtin_amdgcn_mfma_f32_16x16x32_bf16(af0, b0, av[ni], 0, 0, 0);
        av[ni] = __builtin_amdgcn_mfma_f32_16x16x32_bf16(af1, b1, av[ni], 0, 0, 0);
    }

    const int rowb = wid * 16 + g * 4;
    const int b = t0 >> 11, n0 = t0 & (NSEQ - 1);
    const size_t qkbase = ((size_t)(b * NH + h) * NSEQ + n0) * DH;

    #pragma unroll
    for (int ni = 0; ni < 4; ni++) {
        const int col = ni * 16 + c0;
        const float bb = bv[h * 64 + col];
        #pragma unroll
        for (int r = 0; r < 4; r++) {
            int i = rowb + r;
            vts[col * 72 + vperm(i)] = (bf16_t)(av[ni][r] + bb);
        }
    }
    __syncthreads();

    #pragma unroll
    for (int ni = 0; ni < 4; ni++) {
        const int col = ni * 16 + c0;
        const float bb = bq[h * 64 + col];
        #pragma unroll
        for (int r = 0; r < 4; r++)
            h1s[lds_sw(rowb + r, col)] = (bf16_t)((aq[ni][r] + bb) * 0.045084220f);
    }
    __syncthreads();
    {
        const int row = tid >> 2, cp = (tid & 3) * 2;
        *(bf16x8*)(q + qkbase + row * DH + cp * 8) =
            *(const bf16x8*)&h1s[row * 64 + ((cp ^ (row & 7)) << 3)];
        *(bf16x8*)(q + qkbase + row * DH + (cp + 1) * 8) =
            *(const bf16x8*)&h1s[row * 64 + (((cp + 1) ^ (row & 7)) << 3)];
        const int d = tid >> 2, c16 = tid & 3;
        size_t vbase = ((size_t)(b * NH + h) * DH + d) * NSEQ + n0 + c16 * 16;
        *(bf16x8*)(vt + vbase)     = *(const bf16x8*)&vts[d * 72 + c16 * 16];
        *(bf16x8*)(vt + vbase + 8) = *(const bf16x8*)&vts[d * 72 + c16 * 16 + 8];
    }
    __syncthreads();

    #pragma unroll
    for (int ni = 0; ni < 4; ni++) {
        const int col = ni * 16 + c0;
        const float bb = bk[h * 64 + col];
        #pragma unroll
        for (int r = 0; r < 4; r++)
            h1s[lds_sw(rowb + r, col)] = (bf16_t)(ak[ni][r] + bb);
    }
    __syncthreads();
    {
        const int row = tid >> 2, cp = (tid & 3) * 2;
        *(bf16x8*)(k + qkbase + row * DH + cp * 8) =
            *(const bf16x8*)&h1s[row * 64 + ((cp ^ (row & 7)) << 3)];
        *(bf16x8*)(k + qkbase + row * DH + (cp + 1) * 8) =
            *(const bf16x8*)&h1s[row * 64 + (((cp + 1) ^ (row & 7)) << 3)];
    }
}

// ================= K2: bf16 MFMA flash attention (8-wave, 128 q-rows/block) ======
// K/V staging shared by 2x the q-rows: per-CU staged bytes per tile halve.
// Each wave stages one 1KB K-group + one 1KB V-group (grp = wid).
__global__ __launch_bounds__(512, 4) void k_attn(
    const bf16_t* __restrict__ qg, const bf16_t* __restrict__ kg,
    const bf16_t* __restrict__ vt, bf16_t* __restrict__ attnb)
{
    __shared__ __align__(16) bf16_t Ks[2][4096];
    __shared__ __align__(16) bf16_t Vs[2][4096];

    const int bx = blockIdx.x;
    const int bh = ((bx & 7) << 2) | ((bx >> 3) & 3);
    const int qb = blockIdx.y;
    const int tid = threadIdx.x;
    const int wid = tid >> 6, lane = tid & 63;
    const int g = lane >> 4, c0 = lane & 15;
    const int prow = wid * 16 + c0;          // q-row within the 128-block

    bf16x8 aqf[2];
    {
        const int qrow = qb * 128 + prow;
        const bf16_t* qp = qg + ((size_t)bh * NSEQ + qrow) * DH + g * 8;
        aqf[0] = *(const bf16x8*)qp;
        aqf[1] = *(const bf16x8*)(qp + 32);
    }
    bf16x8 ones;
    #pragma unroll
    for (int e = 0; e < 8; e++) ones[e] = (bf16_t)1.0f;

    int soff[4][2];
    #pragma unroll
    for (int cb = 0; cb < 4; cb++)
        #pragma unroll
        for (int kb = 0; kb < 2; kb++) {
            int row = cb * 16 + c0;
            soff[cb][kb] = row * 64 + (((g + (kb << 2)) ^ (row & 7)) << 3);
        }

    // staging geometry: wave wid stages K group wid and V group wid (1KB each)
    const bf16_t* kbase = kg + (size_t)bh * NSEQ * DH;
    const bf16_t* vbase = vt + (size_t)bh * DH * NSEQ;
    const int lc = wid * 64 + lane;
    const int rowS = lc >> 3, ccS = (lc & 7) ^ (rowS & 7);
    const bf16_t* kp = kbase + rowS * DH + ccS * 8;
    const bf16_t* vp = vbase + (size_t)rowS * NSEQ + ccS * 8;

    GLL16(kp, (char*)&Ks[0][0] + (wid << 10));
    GLL16(vp, (char*)&Vs[0][0] + (wid << 10));
    kp += 64 * DH; vp += 64;

    f32x4 O[4];
    #pragma unroll
    for (int cb = 0; cb < 4; cb++) O[cb] = (f32x4){0.f, 0.f, 0.f, 0.f};
    f32x4 l_acc = (f32x4){0.f, 0.f, 0.f, 0.f};

    auto tile = [&](const bf16_t* Kc, const bf16_t* Vc,
                    bf16_t* Kn, bf16_t* Vn, bool pref) {
        __syncthreads();
        if (pref) {
            GLL16(kp, (char*)Kn + (wid << 10));
            GLL16(vp, (char*)Vn + (wid << 10));
            kp += 64 * DH; vp += 64;
        }

        f32x4 S[4];
        #pragma unroll
        for (int cb = 0; cb < 4; cb++) {
            f32x4 acc = (f32x4){0.f, 0.f, 0.f, 0.f};
            acc = __builtin_amdgcn_mfma_f32_16x16x32_bf16(
                *(const bf16x8*)&Kc[soff[cb][0]], aqf[0], acc, 0, 0, 0);
            acc = __builtin_amdgcn_mfma_f32_16x16x32_bf16(
                *(const bf16x8*)&Kc[soff[cb][1]], aqf[1], acc, 0, 0, 0);
            S[cb] = acc;
        }

        bf16x8 pa0, pa1;
        #pragma unroll
        for (int cb = 0; cb < 2; cb++)
            #pragma unroll
            for (int r = 0; r < 4; r++)
                pa0[cb * 4 + r] = (bf16_t)fexp2(S[cb][r]);
        #pragma unroll
        for (int cb = 0; cb < 2; cb++)
            #pragma unroll
            for (int r = 0; r < 4; r++)
                pa1[cb * 4 + r] = (bf16_t)fexp2(S[2 + cb][r]);

        l_acc = __builtin_amdgcn_mfma_f32_16x16x32_bf16(ones, pa0, l_acc, 0, 0, 0);
        l_acc = __builtin_amdgcn_mfma_f32_16x16x32_bf16(ones, pa1, l_acc, 0, 0, 0);

        #pragma unroll
        for (int cb = 0; cb < 4; cb++) {
            f32x4 acc = O[cb];
            acc = __builtin_amdgcn_mfma_f32_16x16x32_bf16(
                *(const bf16x8*)&Vc[soff[cb][0]], pa0, acc, 0, 0, 0);
            acc = __builtin_amdgcn_mfma_f32_16x16x32_bf16(
                *(const bf16x8*)&Vc[soff[cb][1]], pa1, acc, 0, 0, 0);
            O[cb] = acc;
        }
    };

    #pragma unroll 1
    for (int kt2 = 0; kt2 < 16; kt2++) {
        tile(Ks[0], Vs[0], Ks[1], Vs[1], true);
        tile(Ks[1], Vs[1], Ks[0], Vs[0], kt2 < 15);
    }

    // epilogue: O^T -> [128][64] transpose buffer (Ks[0..1] contiguous, 16 KB)
    __syncthreads();
    const float inv = 1.0f / l_acc[0];
    bf16_t* Tb = &Ks[0][0];
    #pragma unroll
    for (int cb = 0; cb < 4; cb++)
        #pragma unroll
        for (int r = 0; r < 4; r++) {
            int d = cb * 16 + g * 4 + r;
            Tb[lds_sw(prow, d)] = (bf16_t)(O[cb][r] * inv);
        }
    __syncthreads();
    {
        const int row = tid >> 2, cp = (tid & 3) * 2;   // row 0..127
        size_t gbase = ((size_t)bh * NSEQ + qb * 128 + row) * DH;
        *(bf16x8*)(attnb + gbase + cp * 8) =
            *(const bf16x8*)&Tb[row * 64 + ((cp ^ (row & 7)) << 3)];
        *(bf16x8*)(attnb + gbase + (cp + 1) * 8) =
            *(const bf16x8*)&Tb[row * 64 + (((cp + 1) ^ (row & 7)) << 3)];
    }
}

// ================= K3: fused proj + residual + LN2 + FFN + residual ==============
// Two-phase staging: barrier 1 covers only wos (8 KB); the 64 KB w1/w2 stream
// is issued after it and drains under proj+LN2 (phase-level T14).
__global__ __launch_bounds__(512, 4) void k_pffn(
    const bf16_t* __restrict__ attnb, const bf16_t* __restrict__ wot,
    const float* __restrict__ bo, const float* __restrict__ x,
    const float* __restrict__ g2, const float* __restrict__ be2,
    const bf16_t* __restrict__ w1t, const float* __restrict__ b1,
    const bf16_t* __restrict__ w2t, const float* __restrict__ b2,
    bf16_t* __restrict__ outp)
{
    __shared__ __align__(16) bf16_t wos[4096];       // 8 KB  (swizzled image)
    __shared__ __align__(16) bf16_t w1s[16384];      // 32 KB (perm+swz image)
    __shared__ __align__(16) bf16_t w2s[16384];      // 32 KB (swizzled image)
    const int fid = blockIdx.x + 32 * blockIdx.y;
    const int rem = (fid & 7) * 64 + (fid >> 3);
    const int h   = rem >> 5;
    const int t0  = (rem & 31) * 128;
    const int tid = threadIdx.x;
    const int wid = tid >> 6, lane = tid & 63;
    const int g = lane >> 4, c0 = lane & 15;
    const int b = t0 >> 11, n0 = t0 & (NSEQ - 1);
    const int tok = t0 + wid * 16 + c0;

    // T14: issue attn/x/bias loads up front.
    const bf16_t* ah = attnb + ((size_t)(b * NH + h) * NSEQ + n0) * DH;
    bf16x8 paf0 = *(const bf16x8*)(ah + (wid * 16 + c0) * DH + g * 8);
    bf16x8 paf1 = *(const bf16x8*)(ah + (wid * 16 + c0) * DH + g * 8 + 32);
    float4 xr4[4], bo4[4];
    #pragma unroll
    for (int ni = 0; ni < 4; ni++) {
        xr4[ni] = *(const float4*)(x + (size_t)tok * FD + h * DH + ni * 16 + g * 4);
        bo4[ni] = *(const float4*)(bo + h * DH + ni * 16 + g * 4);
    }

    const bf16_t* s1 = w1t + (size_t)h * 16384;
    const bf16_t* s2 = w2t + (size_t)h * 16384;
    { // phase 1: stage wos (8 KB) only, then barrier
        const bf16_t* s0 = wot + h * 4096;
        GLL16(s0 + wid * 512 + lane * 8, (char*)wos + (wid << 10));
        __syncthreads();
    }
    { // phase 2: issue w1/w2 staging (64 KB); it drains under proj+LN2
        #pragma unroll
        for (int i = 0; i < 4; i++) {
            int grp = wid * 4 + i;
            GLL16(s1 + grp * 512 + lane * 8, (char*)w1s + (grp << 10));
            GLL16(s2 + grp * 512 + lane * 8, (char*)w2s + (grp << 10));
        }
    }

    // ---- proj (swapped): lane holds o1[tok][f = ni*16 + g*4 + r] ----
    float o1[4][4];
    #pragma unroll
    for (int ni = 0; ni < 4; ni++) {
        f32x4 acc = (f32x4){0.f, 0.f, 0.f, 0.f};
        const int orow = ni * 16 + c0;
        bf16x8 b0  = *(const bf16x8*)&wos[orow * 64 + (((g    ) ^ (orow & 7)) << 3)];
        bf16x8 b1f = *(const bf16x8*)&wos[orow * 64 + (((4 + g) ^ (orow & 7)) << 3)];
        acc = __builtin_amdgcn_mfma_f32_16x16x32_bf16(b0, paf0, acc, 0, 0, 0);
        acc = __builtin_amdgcn_mfma_f32_16x16x32_bf16(b1f, paf1, acc, 0, 0, 0);
        o1[ni][0] = acc[0] + bo4[ni].x + xr4[ni].x;
        o1[ni][1] = acc[1] + bo4[ni].y + xr4[ni].y;
        o1[ni][2] = acc[2] + bo4[ni].z + xr4[ni].z;
        o1[ni][3] = acc[3] + bo4[ni].w + xr4[ni].w;
    }

    // ---- LN2: in-lane 16-sum + 2 shuffles ----
    float s = 0.f;
    #pragma unroll
    for (int ni = 0; ni < 4; ni++)
        #pragma unroll
        for (int r = 0; r < 4; r++) s += o1[ni][r];
    s += __shfl_xor(s, 16);
    s += __shfl_xor(s, 32);
    const float mean = s * (1.0f / 64.0f);
    float v = 0.f;
    #pragma unroll
    for (int ni = 0; ni < 4; ni++)
        #pragma unroll
        for (int r = 0; r < 4; r++) { float d = o1[ni][r] - mean; v += d * d; }
    v += __shfl_xor(v, 16);
    v += __shfl_xor(v, 32);
    const float rstd = rsqrtf(v * (1.0f / 64.0f) + 1e-5f);

    // h2 packed DIRECTLY into GEMM1 B-fragments (w1t k-perm compensates)
    bf16x8 hb0, hb1;
    #pragma unroll
    for (int ni = 0; ni < 4; ni++) {
        const float4 g24 = *(const float4*)(g2 + ni * 16 + g * 4);
        const float4 be4 = *(const float4*)(be2 + ni * 16 + g * 4);
        #pragma unroll
        for (int r = 0; r < 4; r++) {
            float hv = (o1[ni][r] - mean) * rstd * ((const float*)&g24)[r]
                       + ((const float*)&be4)[r];
            if (ni < 2) hb0[(ni & 1) * 4 + r] = (bf16_t)hv;
            else        hb1[(ni & 1) * 4 + r] = (bf16_t)hv;
        }
    }
    __syncthreads();   // barrier 2: w1s/w2s staged (mostly drained already)

    // ---- GEMM1+GEMM2 interleaved per-ub ----
    const float* b1h = b1 + h * 256;
    f32x4 acc2[4];
    #pragma unroll
    for (int nt = 0; nt < 4; nt++) acc2[nt] = (f32x4){0.f, 0.f, 0.f, 0.f};

    #pragma unroll
    for (int ub = 0; ub < 4; ub++) {
        f32x4 a4[4];
        #pragma unroll
        for (int j = 0; j < 4; j++) {
            const int wrow = (ub * 4 + j) * 16 + c0;
            bf16x8 bf0 = *(const bf16x8*)&w1s[wrow * 64 + (((g    ) ^ (wrow & 7)) << 3)];
            bf16x8 bf1 = *(const bf16x8*)&w1s[wrow * 64 + (((4 + g) ^ (wrow & 7)) << 3)];
            f32x4 acc = (f32x4){0.f, 0.f, 0.f, 0.f};
            acc = __builtin_amdgcn_mfma_f32_16x16x32_bf16(bf0, hb0, acc, 0, 0, 0);
            acc = __builtin_amdgcn_mfma_f32_16x16x32_bf16(bf1, hb1, acc, 0, 0, 0);
            a4[j] = acc;
        }
        float4 bb0 = *(const float4*)(b1h + (ub * 4 + 0) * 16 + g * 4);
        float4 bb1 = *(const float4*)(b1h + (ub * 4 + 1) * 16 + g * 4);
        float4 bb2 = *(const float4*)(b1h + (ub * 4 + 2) * 16 + g * 4);
        float4 bb3 = *(const float4*)(b1h + (ub * 4 + 3) * 16 + g * 4);
        bf16x8 p0, p1;
        #pragma unroll
        for (int r = 0; r < 4; r++) {
            p0[r]     = (bf16_t)fgelu(a4[0][r] + ((const float*)&bb0)[r]);
            p0[4 + r] = (bf16_t)fgelu(a4[1][r] + ((const float*)&bb1)[r]);
            p1[r]     = (bf16_t)fgelu(a4[2][r] + ((const float*)&bb2)[r]);
            p1[4 + r] = (bf16_t)fgelu(a4[3][r] + ((const float*)&bb3)[r]);
        }
        #pragma unroll
        for (int nt = 0; nt < 4; nt++) {
            const int vrow = nt * 16 + c0;
            bf16x8 bw0 = *(const bf16x8*)&w2s[vrow * 256 +
                            ((ub * 8 + ((g    ) ^ (vrow & 7))) << 3)];
            bf16x8 bw1 = *(const bf16x8*)&w2s[vrow * 256 +
                            ((ub * 8 + ((g + 4) ^ (vrow & 7))) << 3)];
            acc2[nt] = __builtin_amdgcn_mfma_f32_16x16x32_bf16(bw0, p0, acc2[nt], 0, 0, 0);
            acc2[nt] = __builtin_amdgcn_mfma_f32_16x16x32_bf16(bw1, p1, acc2[nt], 0, 0, 0);
        }
    }

    // ---- epilogue ----
    const float* b2h = b2 + h * 64;
    #pragma unroll
    for (int nt = 0; nt < 4; nt++) {
        const float4 b24 = *(const float4*)(b2h + nt * 16 + g * 4);
        bf16x4 ow;
        ow[0] = (bf16_t)(fgelu(acc2[nt][0] + b24.x) + o1[nt][0]);
        ow[1] = (bf16_t)(fgelu(acc2[nt][1] + b24.y) + o1[nt][1]);
        ow[2] = (bf16_t)(fgelu(acc2[nt][2] + b24.z) + o1[nt][2]);
        ow[3] = (bf16_t)(fgelu(acc2[nt][3] + b24.w) + o1[nt][3]);
        *(bf16x4*)(outp + (size_t)tok * FD + h * DH + nt * 16 + g * 4) = ow;
    }
}

// ================= K5: merge GEMM (bf16 MFMA, gll staging) =================
__global__ __launch_bounds__(256) void k_merge(
    const bf16_t* __restrict__ A, const bf16_t* __restrict__ Wt, const float* __restrict__ bias,
    float* __restrict__ C)
{
    __shared__ __align__(16) bf16_t As[128 * 64];
    __shared__ __align__(16) bf16_t Bs[64 * 64];
    const int n0 = blockIdx.x * 64;
    const int m0 = blockIdx.y * 128;
    const int tid = threadIdx.x;
    const int wid = tid >> 6, lane = tid & 63;
    const int c0 = lane & 15, g = lane >> 4;

    const bf16_t* aS[4]; int aO[4];
    #pragma unroll
    for (int i = 0; i < 4; i++) {
        int grp = wid * 4 + i;
        int lc = grp * 64 + lane;
        int row = lc >> 3, cc = (lc & 7) ^ (row & 7);
        aS[i] = A + (size_t)(m0 + row) * FD + cc * 8;
        aO[i] = grp << 10;
    }
    const bf16_t* bS[2]; int bO[2];
    #pragma unroll
    for (int i = 0; i < 2; i++) {
        int grp = wid * 2 + i;
        int lc = grp * 64 + lane;
        int row = lc >> 3, cc = (lc & 7) ^ (row & 7);
        bS[i] = Wt + (size_t)(n0 + row) * FD + cc * 8;
        bO[i] = grp << 10;
    }

    f32x4 acc[2][4];
    #pragma unroll
    for (int mi = 0; mi < 2; mi++)
        #pragma unroll
        for (int ni = 0; ni < 4; ni++)
            acc[mi][ni] = (f32x4){0.f, 0.f, 0.f, 0.f};

    float bv[4];
    #pragma unroll
    for (int ni = 0; ni < 4; ni++) bv[ni] = bias[n0 + ni * 16 + c0];

    for (int k0 = 0; k0 < FD; k0 += 64) {
        __syncthreads();
        #pragma unroll
        for (int i = 0; i < 4; i++) GLL16(aS[i] + k0, (char*)As + aO[i]);
        #pragma unroll
        for (int i = 0; i < 2; i++) GLL16(bS[i] + k0, (char*)Bs + bO[i]);
        __syncthreads();

        bf16x8 af[2][2];
        #pragma unroll
        for (int mi = 0; mi < 2; mi++)
            #pragma unroll
            for (int kk = 0; kk < 2; kk++) {
                int arow = wid * 32 + mi * 16 + c0;
                int ch = kk * 4 + g;
                af[mi][kk] = *(const bf16x8*)&As[arow * 64 + ((ch ^ (arow & 7)) << 3)];
            }
        bf16x8 bfr[4][2];
        #pragma unroll
        for (int ni = 0; ni < 4; ni++)
            #pragma unroll
            for (int kk = 0; kk < 2; kk++) {
                int brow = ni * 16 + c0;
                int ch = kk * 4 + g;
                bfr[ni][kk] = *(const bf16x8*)&Bs[brow * 64 + ((ch ^ (brow & 7)) << 3)];
            }
        #pragma unroll
        for (int mi = 0; mi < 2; mi++)
            #pragma unroll
            for (int ni = 0; ni < 4; ni++)
                #pragma unroll
                for (int kk = 0; kk < 2; kk++)
                    acc[mi][ni] = __builtin_amdgcn_mfma_f32_16x16x32_bf16(
                        af[mi][kk], bfr[ni][kk], acc[mi][ni], 0, 0, 0);
    }

    #pragma unroll
    for (int mi = 0; mi < 2; mi++)
        #pragma unroll
        for (int r = 0; r < 4; r++) {
            int row = m0 + wid * 32 + mi * 16 + g * 4 + r;
            float* cp = C + (size_t)row * FD + n0;
            #pragma unroll
            for (int ni = 0; ni < 4; ni++)
                cp[ni * 16 + c0] = acc[mi][ni][r] + bv[ni];
        }
}

extern "C" void kernel_launch(void* const* d_in, const int* in_sizes, int n_in,
                              void* d_out, int out_size, void* d_ws, size_t ws_size,
                              hipStream_t stream) {
    const float* x   = (const float*)d_in[0];
    const float* g1  = (const float*)d_in[1];
    const float* be1 = (const float*)d_in[2];
    const float* g2  = (const float*)d_in[3];
    const float* be2 = (const float*)d_in[4];
    const float* wq  = (const float*)d_in[5];
    const float* bq  = (const float*)d_in[6];
    const float* wk  = (const float*)d_in[7];
    const float* bk  = (const float*)d_in[8];
    const float* wv  = (const float*)d_in[9];
    const float* bv  = (const float*)d_in[10];
    const float* wo  = (const float*)d_in[11];
    const float* bo  = (const float*)d_in[12];
    const float* w1  = (const float*)d_in[13];
    const float* b1  = (const float*)d_in[14];
    const float* w2  = (const float*)d_in[15];
    const float* b2  = (const float*)d_in[16];
    const float* wm  = (const float*)d_in[17];
    const float* bm  = (const float*)d_in[18];

    char* wsb = (char*)d_ws;
    bf16_t* qb_   = (bf16_t*)(wsb);                        // 8 MB
    bf16_t* kb_   = (bf16_t*)(wsb + (size_t)8  * 1048576); // 8 MB
    bf16_t* vtb   = (bf16_t*)(wsb + (size_t)16 * 1048576); // 8 MB
    bf16_t* attnb = (bf16_t*)(wsb + (size_t)24 * 1048576); // 8 MB ([B,H,N,DH] bf16)
    bf16_t* out2  = (bf16_t*)(wsb + (size_t)40 * 1048576); // 8 MB (FFN output, merge input)
    bf16_t* wtb   = (bf16_t*)(wsb + (size_t)56 * 1048576); // 2 MB
    bf16_t* w1tb  = (bf16_t*)(wsb + (size_t)58 * 1048576); // 512 KB
    bf16_t* w2tb  = (bf16_t*)(wsb + (size_t)58 * 1048576 + 524288); // 512 KB
    bf16_t* wqtb  = (bf16_t*)(wsb + (size_t)59 * 1048576);            // 128 KB
    bf16_t* wktb  = (bf16_t*)(wsb + (size_t)59 * 1048576 + 131072);   // 128 KB
    bf16_t* wvtb  = (bf16_t*)(wsb + (size_t)59 * 1048576 + 262144);   // 128 KB
    bf16_t* wotb  = (bf16_t*)(wsb + (size_t)59 * 1048576 + 393216);   // 128 KB

    k_prep<<<dim3(400), 256, 0, stream>>>(wm, w1, w2, wq, wk, wv, wo,
                                          wtb, w1tb, w2tb, wqtb, wktb, wvtb, wotb);
    k_ln1_qkv<<<dim3(TOKS / 64, NH), 256, 0, stream>>>(x, g1, be1, wqtb, bq, wktb, bk, wvtb, bv,
                                                       qb_, kb_, vtb);
    k_attn<<<dim3(32, NSEQ / 128), 512, 0, stream>>>(qb_, kb_, vtb, attnb);
    k_pffn<<<dim3(32, 16), 512, 0, stream>>>(attnb, wotb, bo, x, g2, be2,
                                             w1tb, b1, w2tb, b2, out2);
    k_merge<<<dim3(FD / 64, TOKS / 128), 256, 0, stream>>>(out2, wtb, bm, (float*)d_out);
}

// Round 22
// 100.381 us; speedup vs baseline: 1.0635x; 1.0034x over previous
//
#include <hip/hip_runtime.h>
#include <hip/hip_bf16.h>
#include <math.h>

#define TOKS 4096
#define NSEQ 2048
#define NH 16
#define DH 64
#define FD 1024

typedef __bf16 bf16_t;
typedef bf16_t bf16x4 __attribute__((ext_vector_type(4)));
typedef bf16_t bf16x8 __attribute__((ext_vector_type(8)));
typedef float f32x4 __attribute__((ext_vector_type(4)));

// async global->LDS, 16B per lane; LDS dest = wave-uniform base + lane*16
#define GLL16(gsrc, ldst)                                                        \
    __builtin_amdgcn_global_load_lds(                                            \
        (const __attribute__((address_space(1))) void*)(const void*)(gsrc),      \
        (__attribute__((address_space(3))) void*)(void*)(ldst), 16, 0, 0)

__device__ __forceinline__ float geluf(float x) {
    return 0.5f * x * (1.0f + erff(x * 0.70710678118654752f));
}

// Schraudolph-style fast exp2: fma + int-cvt; max rel err ~3.5%.
__device__ __forceinline__ float fexp2(float x) {
    int i = (int)__builtin_fmaf(x, 8388608.0f, 1065063216.0f);
    return __int_as_float(i);
}

// fast gelu: x * sigmoid(1.702 x); sigmoid via fexp2 + hw rcp.
__device__ __forceinline__ float fgelu(float x) {
    float e = fexp2(-2.4554542f * x);          // e^{-1.702x}
    return x * __builtin_amdgcn_rcpf(1.0f + e);
}

// scalar swizzled address into a [64][64] bf16 tile (chunk-XOR swizzle)
__device__ __forceinline__ int lds_sw(int row, int d) {
    return row * 64 + ((((d >> 3) ^ (row & 7)) & 7) << 3) + (d & 7);
}

// fragment permutation: j = cb*16 + g*4 + r  ->  (cb>>1)*32 + g*8 + (cb&1)*4 + r
__device__ __forceinline__ int vperm(int j) {
    return (j & 32) | ((j & 12) << 1) | ((j & 16) >> 2) | (j & 3);
}

// ================= K0: fused weight prep =================
__global__ __launch_bounds__(256) void k_prep(
    const float* __restrict__ wm, const float* __restrict__ w1, const float* __restrict__ w2,
    const float* __restrict__ wq, const float* __restrict__ wk,
    const float* __restrict__ wv, const float* __restrict__ wo,
    bf16_t* __restrict__ wt, bf16_t* __restrict__ w1t, bf16_t* __restrict__ w2t,
    bf16_t* __restrict__ wqt, bf16_t* __restrict__ wkt,
    bf16_t* __restrict__ wvt, bf16_t* __restrict__ wot)
{
    __shared__ bf16_t t[64 * 65];
    const int b = blockIdx.x;
    const int tid = threadIdx.x;
    if (b < 256) {                 // wm [k][n] -> wt [n][k]
        const int k0 = (b & 15) * 64, n0 = (b >> 4) * 64;
        #pragma unroll
        for (int it = 0; it < 16; it++) {
            int idx = it * 256 + tid;
            int kk = idx >> 6, nn = idx & 63;
            t[nn * 65 + kk] = (bf16_t)wm[(size_t)(k0 + kk) * FD + n0 + nn];
        }
        __syncthreads();
        #pragma unroll
        for (int it = 0; it < 16; it++) {
            int idx = it * 256 + tid;
            int nn = idx >> 6, kk = idx & 63;
            wt[(size_t)(n0 + nn) * FD + k0 + kk] = t[nn * 65 + kk];
        }
    } else if (b < 320) {          // w1 -> w1t image [h][n=256][k-slot perm + swz]
        const int lb = b - 256;
        const int h = lb >> 2, n0 = (lb & 3) * 64;
        const float* src = w1 + (size_t)h * 64 * 256;
        #pragma unroll
        for (int it = 0; it < 16; it++) {
            int idx = it * 256 + tid;
            int kk = idx >> 6, nn = idx & 63;
            t[nn * 65 + kk] = (bf16_t)src[kk * 256 + n0 + nn];
        }
        __syncthreads();
        bf16_t* dst = w1t + (size_t)h * 16384;
        #pragma unroll
        for (int it = 0; it < 16; it++) {
            int idx = it * 256 + tid;
            int nn = idx >> 6, kpos = idx & 63;
            int kb = kpos >> 5, gg = (kpos >> 3) & 3, e = kpos & 7;
            int f = (kb * 2 + (e >> 2)) * 16 + gg * 4 + (e & 3);
            int row = n0 + nn;
            dst[row * 64 + ((((kpos >> 3) ^ (row & 7)) & 7) << 3) + (kpos & 7)] =
                t[nn * 65 + f];
        }
    } else if (b < 384) {          // w2 [h][256][64] -> w2t image [h][n=64][k'=256 swz]
        const int lb = b - 320;
        const int h = lb >> 2, k0 = (lb & 3) * 64;
        const float* src = w2 + (size_t)h * 256 * 64;
        #pragma unroll
        for (int it = 0; it < 16; it++) {
            int idx = it * 256 + tid;
            int kk = idx >> 6, nn = idx & 63;
            t[nn * 65 + kk] = (bf16_t)src[(k0 + kk) * 64 + nn];
        }
        __syncthreads();
        bf16_t* dst = w2t + (size_t)h * 16384;
        #pragma unroll
        for (int it = 0; it < 16; it++) {
            int idx = it * 256 + tid;
            int nn = idx >> 6, kk = idx & 63;
            int c = k0 + vperm(kk);
            int chunk = c >> 3;
            int chunkp = (chunk & 24) | ((chunk ^ nn) & 7);
            dst[nn * 256 + (chunkp << 3) + (c & 7)] = t[nn * 65 + kk];
        }
    } else {                       // wq/wk/wv plain [h][g][f]; wo -> swizzled image
        const int h = b - 384;
        const float* srcs[4] = {wq + h * 4096, wk + h * 4096, wv + h * 4096, wo + h * 4096};
        bf16_t* dsts[4] = {wqt + h * 4096, wkt + h * 4096, wvt + h * 4096, wot + h * 4096};
        #pragma unroll
        for (int m = 0; m < 4; m++) {
            __syncthreads();
            #pragma unroll
            for (int it = 0; it < 16; it++) {
                int idx = it * 256 + tid;
                int ff = idx >> 6, gg = idx & 63;
                t[gg * 65 + ff] = (bf16_t)srcs[m][ff * 64 + gg];
            }
            __syncthreads();
            #pragma unroll
            for (int it = 0; it < 16; it++) {
                int idx = it * 256 + tid;
                int gg = idx >> 6, ff = idx & 63;
                if (m == 3)
                    dsts[m][gg * 64 + ((((ff >> 3) ^ (gg & 7)) & 7) << 3) + (ff & 7)] =
                        t[gg * 65 + ff];
                else
                    dsts[m][gg * 64 + ff] = t[gg * 65 + ff];
            }
        }
    }
}

// ================= K1: LN1 + QKV projections (bf16 MFMA) =================
__global__ __launch_bounds__(256) void k_ln1_qkv(
    const float* __restrict__ x, const float* __restrict__ g1, const float* __restrict__ be1,
    const bf16_t* __restrict__ wqt, const float* __restrict__ bq,
    const bf16_t* __restrict__ wkt, const float* __restrict__ bk,
    const bf16_t* __restrict__ wvt, const float* __restrict__ bv,
    bf16_t* __restrict__ q, bf16_t* __restrict__ k, bf16_t* __restrict__ vt)
{
    __shared__ __align__(16) bf16_t h1s[64 * 64];
    __shared__ __align__(16) bf16_t vts[64 * 72];
    const int h  = blockIdx.y;
    const int t0 = blockIdx.x * 64;
    const int tid = threadIdx.x;

    {
        const int i = tid >> 2, s = tid & 3;
        const float* xr = x + (size_t)(t0 + i) * FD + h * DH + s * 16;
        float vals[16];
        #pragma unroll
        for (int r = 0; r < 4; r++) {
            float4 tmp = *(const float4*)(xr + r * 4);
            vals[r*4+0]=tmp.x; vals[r*4+1]=tmp.y; vals[r*4+2]=tmp.z; vals[r*4+3]=tmp.w;
        }
        float sm = 0.f;
        #pragma unroll
        for (int r = 0; r < 16; r++) sm += vals[r];
        sm += __shfl_xor(sm, 1); sm += __shfl_xor(sm, 2);
        const float mean = sm * (1.0f / 64.0f);
        float vr = 0.f;
        #pragma unroll
        for (int r = 0; r < 16; r++) { float d = vals[r] - mean; vr += d * d; }
        vr += __shfl_xor(vr, 1); vr += __shfl_xor(vr, 2);
        const float rstd = rsqrtf(vr * (1.0f / 64.0f) + 1e-5f);
        bf16x8 o0, o1;
        #pragma unroll
        for (int r = 0; r < 8; r++) {
            int d0 = s * 16 + r, d1 = s * 16 + 8 + r;
            o0[r] = (bf16_t)((vals[r]     - mean) * rstd * g1[d0] + be1[d0]);
            o1[r] = (bf16_t)((vals[8 + r] - mean) * rstd * g1[d1] + be1[d1]);
        }
        *(bf16x8*)&h1s[i * 64 + (((s * 2 + 0) ^ (i & 7)) << 3)] = o0;
        *(bf16x8*)&h1s[i * 64 + (((s * 2 + 1) ^ (i & 7)) << 3)] = o1;
    }
    __syncthreads();

    const int wid = tid >> 6, lane = tid & 63;
    const int g = lane >> 4, c0 = lane & 15;
    const int arow = wid * 16 + c0;

    bf16x8 af0 = *(const bf16x8*)&h1s[arow * 64 + (((g    ) ^ (arow & 7)) << 3)];
    bf16x8 af1 = *(const bf16x8*)&h1s[arow * 64 + (((4 + g) ^ (arow & 7)) << 3)];

    const bf16_t* wqh = wqt + h * 4096;
    const bf16_t* wkh = wkt + h * 4096;
    const bf16_t* wvh = wvt + h * 4096;
    f32x4 aq[4], ak[4], av[4];
    #pragma unroll
    for (int ni = 0; ni < 4; ni++) {
        aq[ni] = (f32x4){0.f, 0.f, 0.f, 0.f};
        ak[ni] = (f32x4){0.f, 0.f, 0.f, 0.f};
        av[ni] = (f32x4){0.f, 0.f, 0.f, 0.f};
    }
    #pragma unroll
    for (int ni = 0; ni < 4; ni++) {
        const int col = ni * 16 + c0;
        bf16x8 b0, b1;
        b0 = *(const bf16x8*)(wqh + col * 64 + g * 8);
        b1 = *(const bf16x8*)(wqh + col * 64 + g * 8 + 32);
        aq[ni] = __builtin_amdgcn_mfma_f32_16x16x32_bf16(af0, b0, aq[ni], 0, 0, 0);
        aq[ni] = __builtin_amdgcn_mfma_f32_16x16x32_bf16(af1, b1, aq[ni], 0, 0, 0);
        b0 = *(const bf16x8*)(wkh + col * 64 + g * 8);
        b1 = *(const bf16x8*)(wkh + col * 64 + g * 8 + 32);
        ak[ni] = __builtin_amdgcn_mfma_f32_16x16x32_bf16(af0, b0, ak[ni], 0, 0, 0);
        ak[ni] = __builtin_amdgcn_mfma_f32_16x16x32_bf16(af1, b1, ak[ni], 0, 0, 0);
        b0 = *(const bf16x8*)(wvh + col * 64 + g * 8);
        b1 = *(const bf16x8*)(wvh + col * 64 + g * 8 + 32);
        av[ni] = __builtin_amdgcn_mfma_f32_16x16x32_bf16(af0, b0, av[ni], 0, 0, 0);
        av[ni] = __builtin_amdgcn_mfma_f32_16x16x32_bf16(af1, b1, av[ni], 0, 0, 0);
    }

    const int rowb = wid * 16 + g * 4;
    const int b = t0 >> 11, n0 = t0 & (NSEQ - 1);
    const size_t qkbase = ((size_t)(b * NH + h) * NSEQ + n0) * DH;

    #pragma unroll
    for (int ni = 0; ni < 4; ni++) {
        const int col = ni * 16 + c0;
        const float bb = bv[h * 64 + col];
        #pragma unroll
        for (int r = 0; r < 4; r++) {
            int i = rowb + r;
            vts[col * 72 + vperm(i)] = (bf16_t)(av[ni][r] + bb);
        }
    }
    __syncthreads();

    #pragma unroll
    for (int ni = 0; ni < 4; ni++) {
        const int col = ni * 16 + c0;
        const float bb = bq[h * 64 + col];
        #pragma unroll
        for (int r = 0; r < 4; r++)
            h1s[lds_sw(rowb + r, col)] = (bf16_t)((aq[ni][r] + bb) * 0.045084220f);
    }
    __syncthreads();
    {
        const int row = tid >> 2, cp = (tid & 3) * 2;
        *(bf16x8*)(q + qkbase + row * DH + cp * 8) =
            *(const bf16x8*)&h1s[row * 64 + ((cp ^ (row & 7)) << 3)];
        *(bf16x8*)(q + qkbase + row * DH + (cp + 1) * 8) =
            *(const bf16x8*)&h1s[row * 64 + (((cp + 1) ^ (row & 7)) << 3)];
        const int d = tid >> 2, c16 = tid & 3;
        size_t vbase = ((size_t)(b * NH + h) * DH + d) * NSEQ + n0 + c16 * 16;
        *(bf16x8*)(vt + vbase)     = *(const bf16x8*)&vts[d * 72 + c16 * 16];
        *(bf16x8*)(vt + vbase + 8) = *(const bf16x8*)&vts[d * 72 + c16 * 16 + 8];
    }
    __syncthreads();

    #pragma unroll
    for (int ni = 0; ni < 4; ni++) {
        const int col = ni * 16 + c0;
        const float bb = bk[h * 64 + col];
        #pragma unroll
        for (int r = 0; r < 4; r++)
            h1s[lds_sw(rowb + r, col)] = (bf16_t)(ak[ni][r] + bb);
    }
    __syncthreads();
    {
        const int row = tid >> 2, cp = (tid & 3) * 2;
        *(bf16x8*)(k + qkbase + row * DH + cp * 8) =
            *(const bf16x8*)&h1s[row * 64 + ((cp ^ (row & 7)) << 3)];
        *(bf16x8*)(k + qkbase + row * DH + (cp + 1) * 8) =
            *(const bf16x8*)&h1s[row * 64 + (((cp + 1) ^ (row & 7)) << 3)];
    }
}

// ================= K2: bf16 MFMA flash attention (8-wave, KVBLK=128) ============
// Each buffer = two [64][64] K-tiles + two V-tiles (16 KB/side). One barrier per
// 128 j-rows (16 total, was 32); prefetch drains under 2x compute.
__global__ __launch_bounds__(512, 4) void k_attn(
    const bf16_t* __restrict__ qg, const bf16_t* __restrict__ kg,
    const bf16_t* __restrict__ vt, bf16_t* __restrict__ attnb)
{
    __shared__ __align__(16) bf16_t Ks[2][8192];
    __shared__ __align__(16) bf16_t Vs[2][8192];

    const int bx = blockIdx.x;
    const int bh = ((bx & 7) << 2) | ((bx >> 3) & 3);
    const int qb = blockIdx.y;
    const int tid = threadIdx.x;
    const int wid = tid >> 6, lane = tid & 63;
    const int g = lane >> 4, c0 = lane & 15;
    const int prow = wid * 16 + c0;          // q-row within the 128-block

    bf16x8 aqf[2];
    {
        const int qrow = qb * 128 + prow;
        const bf16_t* qp = qg + ((size_t)bh * NSEQ + qrow) * DH + g * 8;
        aqf[0] = *(const bf16x8*)qp;
        aqf[1] = *(const bf16x8*)(qp + 32);
    }
    bf16x8 ones;
    #pragma unroll
    for (int e = 0; e < 8; e++) ones[e] = (bf16_t)1.0f;

    int soff[4][2];
    #pragma unroll
    for (int cb = 0; cb < 4; cb++)
        #pragma unroll
        for (int kb = 0; kb < 2; kb++) {
            int row = cb * 16 + c0;
            soff[cb][kb] = row * 64 + (((g + (kb << 2)) ^ (row & 7)) << 3);
        }

    // staging geometry: wave wid stages K groups {wid, wid+8}, V groups {wid, wid+8}.
    // K: 128 rows contiguous. V: group grp -> tile (grp>>3), d-rows (grp&7)*8.. .
    const bf16_t* kbase = kg + (size_t)bh * NSEQ * DH;
    const bf16_t* vbase = vt + (size_t)bh * DH * NSEQ;
    const int lcK0 = wid * 64 + lane;               // K group wid
    const int rK0 = lcK0 >> 3, cK0 = (lcK0 & 7) ^ (rK0 & 7);
    const int rK1 = rK0 + 64;                       // K group wid+8 (rows +64)
    const int cK1 = (lcK0 & 7) ^ (rK1 & 7);
    const int lcV = (wid & 7) * 64 + lane;          // V d-row pattern
    const int rV = lcV >> 3, cV = (lcV & 7) ^ (rV & 7);
    const bf16_t* kp0 = kbase + rK0 * DH + cK0 * 8;
    const bf16_t* kp1 = kbase + rK1 * DH + cK1 * 8;
    const bf16_t* vp0 = vbase + (size_t)rV * NSEQ + cV * 8;        // tile 0 (j 0..63)
    const bf16_t* vp1 = vbase + (size_t)rV * NSEQ + 64 + cV * 8;   // tile 1 (j 64..127)

    GLL16(kp0, (char*)&Ks[0][0] + (wid << 10));
    GLL16(kp1, (char*)&Ks[0][0] + ((wid + 8) << 10));
    GLL16(vp0, (char*)&Vs[0][0] + (wid << 10));
    GLL16(vp1, (char*)&Vs[0][0] + ((wid + 8) << 10));
    kp0 += 128 * DH; kp1 += 128 * DH; vp0 += 128; vp1 += 128;

    f32x4 O[4];
    #pragma unroll
    for (int cb = 0; cb < 4; cb++) O[cb] = (f32x4){0.f, 0.f, 0.f, 0.f};
    f32x4 l_acc = (f32x4){0.f, 0.f, 0.f, 0.f};

    auto tile = [&](const bf16_t* Kc, const bf16_t* Vc,
                    bf16_t* Kn, bf16_t* Vn, bool pref) {
        __syncthreads();            // drains pending gll -> current buf ready
        if (pref) {
            GLL16(kp0, (char*)Kn + (wid << 10));
            GLL16(kp1, (char*)Kn + ((wid + 8) << 10));
            GLL16(vp0, (char*)Vn + (wid << 10));
            GLL16(vp1, (char*)Vn + ((wid + 8) << 10));
            kp0 += 128 * DH; kp1 += 128 * DH; vp0 += 128; vp1 += 128;
        }

        #pragma unroll
        for (int s = 0; s < 2; s++) {
            const bf16_t* Kt = Kc + s * 4096;
            const bf16_t* Vt = Vc + s * 4096;
            f32x4 S[4];
            #pragma unroll
            for (int cb = 0; cb < 4; cb++) {
                f32x4 acc = (f32x4){0.f, 0.f, 0.f, 0.f};
                acc = __builtin_amdgcn_mfma_f32_16x16x32_bf16(
                    *(const bf16x8*)&Kt[soff[cb][0]], aqf[0], acc, 0, 0, 0);
                acc = __builtin_amdgcn_mfma_f32_16x16x32_bf16(
                    *(const bf16x8*)&Kt[soff[cb][1]], aqf[1], acc, 0, 0, 0);
                S[cb] = acc;
            }

            bf16x8 pa0, pa1;
            #pragma unroll
            for (int cb = 0; cb < 2; cb++)
                #pragma unroll
                for (int r = 0; r < 4; r++)
                    pa0[cb * 4 + r] = (bf16_t)fexp2(S[cb][r]);
            #pragma unroll
            for (int cb = 0; cb < 2; cb++)
                #pragma unroll
                for (int r = 0; r < 4; r++)
                    pa1[cb * 4 + r] = (bf16_t)fexp2(S[2 + cb][r]);

            l_acc = __builtin_amdgcn_mfma_f32_16x16x32_bf16(ones, pa0, l_acc, 0, 0, 0);
            l_acc = __builtin_amdgcn_mfma_f32_16x16x32_bf16(ones, pa1, l_acc, 0, 0, 0);

            #pragma unroll
            for (int cb = 0; cb < 4; cb++) {
                f32x4 acc = O[cb];
                acc = __builtin_amdgcn_mfma_f32_16x16x32_bf16(
                    *(const bf16x8*)&Vt[soff[cb][0]], pa0, acc, 0, 0, 0);
                acc = __builtin_amdgcn_mfma_f32_16x16x32_bf16(
                    *(const bf16x8*)&Vt[soff[cb][1]], pa1, acc, 0, 0, 0);
                O[cb] = acc;
            }
        }
    };

    #pragma unroll 1
    for (int kt2 = 0; kt2 < 8; kt2++) {
        tile(Ks[0], Vs[0], Ks[1], Vs[1], true);
        tile(Ks[1], Vs[1], Ks[0], Vs[0], kt2 < 7);
    }

    // epilogue: O^T -> [128][64] transpose buffer (Ks[0] is 16 KB)
    __syncthreads();
    const float inv = 1.0f / l_acc[0];
    bf16_t* Tb = &Ks[0][0];
    #pragma unroll
    for (int cb = 0; cb < 4; cb++)
        #pragma unroll
        for (int r = 0; r < 4; r++) {
            int d = cb * 16 + g * 4 + r;
            Tb[lds_sw(prow, d)] = (bf16_t)(O[cb][r] * inv);
        }
    __syncthreads();
    {
        const int row = tid >> 2, cp = (tid & 3) * 2;   // row 0..127
        size_t gbase = ((size_t)bh * NSEQ + qb * 128 + row) * DH;
        *(bf16x8*)(attnb + gbase + cp * 8) =
            *(const bf16x8*)&Tb[row * 64 + ((cp ^ (row & 7)) << 3)];
        *(bf16x8*)(attnb + gbase + (cp + 1) * 8) =
            *(const bf16x8*)&Tb[row * 64 + (((cp + 1) ^ (row & 7)) << 3)];
    }
}

// ================= K3: fused proj + residual + LN2 + FFN + residual ==============
__global__ __launch_bounds__(512, 4) void k_pffn(
    const bf16_t* __restrict__ attnb, const bf16_t* __restrict__ wot,
    const float* __restrict__ bo, const float* __restrict__ x,
    const float* __restrict__ g2, const float* __restrict__ be2,
    const bf16_t* __restrict__ w1t, const float* __restrict__ b1,
    const bf16_t* __restrict__ w2t, const float* __restrict__ b2,
    bf16_t* __restrict__ outp)
{
    __shared__ __align__(16) bf16_t wos[4096];       // 8 KB  (swizzled image)
    __shared__ __align__(16) bf16_t w1s[16384];      // 32 KB (perm+swz image)
    __shared__ __align__(16) bf16_t w2s[16384];      // 32 KB (swizzled image)
    const int fid = blockIdx.x + 32 * blockIdx.y;
    const int rem = (fid & 7) * 64 + (fid >> 3);
    const int h   = rem >> 5;
    const int t0  = (rem & 31) * 128;
    const int tid = threadIdx.x;
    const int wid = tid >> 6, lane = tid & 63;
    const int g = lane >> 4, c0 = lane & 15;
    const int b = t0 >> 11, n0 = t0 & (NSEQ - 1);
    const int tok = t0 + wid * 16 + c0;

    // T14: issue attn/x/bias loads up front.
    const bf16_t* ah = attnb + ((size_t)(b * NH + h) * NSEQ + n0) * DH;
    bf16x8 paf0 = *(const bf16x8*)(ah + (wid * 16 + c0) * DH + g * 8);
    bf16x8 paf1 = *(const bf16x8*)(ah + (wid * 16 + c0) * DH + g * 8 + 32);
    float4 xr4[4], bo4[4];
    #pragma unroll
    for (int ni = 0; ni < 4; ni++) {
        xr4[ni] = *(const float4*)(x + (size_t)tok * FD + h * DH + ni * 16 + g * 4);
        bo4[ni] = *(const float4*)(bo + h * DH + ni * 16 + g * 4);
    }

    const bf16_t* s1 = w1t + (size_t)h * 16384;
    const bf16_t* s2 = w2t + (size_t)h * 16384;
    { // phase 1: stage wos (8 KB) only, then barrier
        const bf16_t* s0 = wot + h * 4096;
        GLL16(s0 + wid * 512 + lane * 8, (char*)wos + (wid << 10));
        __syncthreads();
    }
    { // phase 2: issue w1/w2 staging (64 KB); it drains under proj+LN2
        #pragma unroll
        for (int i = 0; i < 4; i++) {
            int grp = wid * 4 + i;
            GLL16(s1 + grp * 512 + lane * 8, (char*)w1s + (grp << 10));
            GLL16(s2 + grp * 512 + lane * 8, (char*)w2s + (grp << 10));
        }
    }

    // ---- proj (swapped): lane holds o1[tok][f = ni*16 + g*4 + r] ----
    float o1[4][4];
    #pragma unroll
    for (int ni = 0; ni < 4; ni++) {
        f32x4 acc = (f32x4){0.f, 0.f, 0.f, 0.f};
        const int orow = ni * 16 + c0;
        bf16x8 b0  = *(const bf16x8*)&wos[orow * 64 + (((g    ) ^ (orow & 7)) << 3)];
        bf16x8 b1f = *(const bf16x8*)&wos[orow * 64 + (((4 + g) ^ (orow & 7)) << 3)];
        acc = __builtin_amdgcn_mfma_f32_16x16x32_bf16(b0, paf0, acc, 0, 0, 0);
        acc = __builtin_amdgcn_mfma_f32_16x16x32_bf16(b1f, paf1, acc, 0, 0, 0);
        o1[ni][0] = acc[0] + bo4[ni].x + xr4[ni].x;
        o1[ni][1] = acc[1] + bo4[ni].y + xr4[ni].y;
        o1[ni][2] = acc[2] + bo4[ni].z + xr4[ni].z;
        o1[ni][3] = acc[3] + bo4[ni].w + xr4[ni].w;
    }

    // ---- LN2: in-lane 16-sum + 2 shuffles ----
    float s = 0.f;
    #pragma unroll
    for (int ni = 0; ni < 4; ni++)
        #pragma unroll
        for (int r = 0; r < 4; r++) s += o1[ni][r];
    s += __shfl_xor(s, 16);
    s += __shfl_xor(s, 32);
    const float mean = s * (1.0f / 64.0f);
    float v = 0.f;
    #pragma unroll
    for (int ni = 0; ni < 4; ni++)
        #pragma unroll
        for (int r = 0; r < 4; r++) { float d = o1[ni][r] - mean; v += d * d; }
    v += __shfl_xor(v, 16);
    v += __shfl_xor(v, 32);
    const float rstd = rsqrtf(v * (1.0f / 64.0f) + 1e-5f);

    // h2 packed DIRECTLY into GEMM1 B-fragments (w1t k-perm compensates)
    bf16x8 hb0, hb1;
    #pragma unroll
    for (int ni = 0; ni < 4; ni++) {
        const float4 g24 = *(const float4*)(g2 + ni * 16 + g * 4);
        const float4 be4 = *(const float4*)(be2 + ni * 16 + g * 4);
        #pragma unroll
        for (int r = 0; r < 4; r++) {
            float hv = (o1[ni][r] - mean) * rstd * ((const float*)&g24)[r]
                       + ((const float*)&be4)[r];
            if (ni < 2) hb0[(ni & 1) * 4 + r] = (bf16_t)hv;
            else        hb1[(ni & 1) * 4 + r] = (bf16_t)hv;
        }
    }
    __syncthreads();   // barrier 2: w1s/w2s staged (mostly drained already)

    // ---- GEMM1+GEMM2 interleaved per-ub ----
    const float* b1h = b1 + h * 256;
    f32x4 acc2[4];
    #pragma unroll
    for (int nt = 0; nt < 4; nt++) acc2[nt] = (f32x4){0.f, 0.f, 0.f, 0.f};

    #pragma unroll
    for (int ub = 0; ub < 4; ub++) {
        f32x4 a4[4];
        #pragma unroll
        for (int j = 0; j < 4; j++) {
            const int wrow = (ub * 4 + j) * 16 + c0;
            bf16x8 bf0 = *(const bf16x8*)&w1s[wrow * 64 + (((g    ) ^ (wrow & 7)) << 3)];
            bf16x8 bf1 = *(const bf16x8*)&w1s[wrow * 64 + (((4 + g) ^ (wrow & 7)) << 3)];
            f32x4 acc = (f32x4){0.f, 0.f, 0.f, 0.f};
            acc = __builtin_amdgcn_mfma_f32_16x16x32_bf16(bf0, hb0, acc, 0, 0, 0);
            acc = __builtin_amdgcn_mfma_f32_16x16x32_bf16(bf1, hb1, acc, 0, 0, 0);
            a4[j] = acc;
        }
        float4 bb0 = *(const float4*)(b1h + (ub * 4 + 0) * 16 + g * 4);
        float4 bb1 = *(const float4*)(b1h + (ub * 4 + 1) * 16 + g * 4);
        float4 bb2 = *(const float4*)(b1h + (ub * 4 + 2) * 16 + g * 4);
        float4 bb3 = *(const float4*)(b1h + (ub * 4 + 3) * 16 + g * 4);
        bf16x8 p0, p1;
        #pragma unroll
        for (int r = 0; r < 4; r++) {
            p0[r]     = (bf16_t)fgelu(a4[0][r] + ((const float*)&bb0)[r]);
            p0[4 + r] = (bf16_t)fgelu(a4[1][r] + ((const float*)&bb1)[r]);
            p1[r]     = (bf16_t)fgelu(a4[2][r] + ((const float*)&bb2)[r]);
            p1[4 + r] = (bf16_t)fgelu(a4[3][r] + ((const float*)&bb3)[r]);
        }
        #pragma unroll
        for (int nt = 0; nt < 4; nt++) {
            const int vrow = nt * 16 + c0;
            bf16x8 bw0 = *(const bf16x8*)&w2s[vrow * 256 +
                            ((ub * 8 + ((g    ) ^ (vrow & 7))) << 3)];
            bf16x8 bw1 = *(const bf16x8*)&w2s[vrow * 256 +
                            ((ub * 8 + ((g + 4) ^ (vrow & 7))) << 3)];
            acc2[nt] = __builtin_amdgcn_mfma_f32_16x16x32_bf16(bw0, p0, acc2[nt], 0, 0, 0);
            acc2[nt] = __builtin_amdgcn_mfma_f32_16x16x32_bf16(bw1, p1, acc2[nt], 0, 0, 0);
        }
    }

    // ---- epilogue ----
    const float* b2h = b2 + h * 64;
    #pragma unroll
    for (int nt = 0; nt < 4; nt++) {
        const float4 b24 = *(const float4*)(b2h + nt * 16 + g * 4);
        bf16x4 ow;
        ow[0] = (bf16_t)(fgelu(acc2[nt][0] + b24.x) + o1[nt][0]);
        ow[1] = (bf16_t)(fgelu(acc2[nt][1] + b24.y) + o1[nt][1]);
        ow[2] = (bf16_t)(fgelu(acc2[nt][2] + b24.z) + o1[nt][2]);
        ow[3] = (bf16_t)(fgelu(acc2[nt][3] + b24.w) + o1[nt][3]);
        *(bf16x4*)(outp + (size_t)tok * FD + h * DH + nt * 16 + g * 4) = ow;
    }
}

// ================= K5: merge GEMM (bf16 MFMA, gll staging) =================
__global__ __launch_bounds__(256) void k_merge(
    const bf16_t* __restrict__ A, const bf16_t* __restrict__ Wt, const float* __restrict__ bias,
    float* __restrict__ C)
{
    __shared__ __align__(16) bf16_t As[128 * 64];
    __shared__ __align__(16) bf16_t Bs[64 * 64];
    const int n0 = blockIdx.x * 64;
    const int m0 = blockIdx.y * 128;
    const int tid = threadIdx.x;
    const int wid = tid >> 6, lane = tid & 63;
    const int c0 = lane & 15, g = lane >> 4;

    const bf16_t* aS[4]; int aO[4];
    #pragma unroll
    for (int i = 0; i < 4; i++) {
        int grp = wid * 4 + i;
        int lc = grp * 64 + lane;
        int row = lc >> 3, cc = (lc & 7) ^ (row & 7);
        aS[i] = A + (size_t)(m0 + row) * FD + cc * 8;
        aO[i] = grp << 10;
    }
    const bf16_t* bS[2]; int bO[2];
    #pragma unroll
    for (int i = 0; i < 2; i++) {
        int grp = wid * 2 + i;
        int lc = grp * 64 + lane;
        int row = lc >> 3, cc = (lc & 7) ^ (row & 7);
        bS[i] = Wt + (size_t)(n0 + row) * FD + cc * 8;
        bO[i] = grp << 10;
    }

    f32x4 acc[2][4];
    #pragma unroll
    for (int mi = 0; mi < 2; mi++)
        #pragma unroll
        for (int ni = 0; ni < 4; ni++)
            acc[mi][ni] = (f32x4){0.f, 0.f, 0.f, 0.f};

    float bv[4];
    #pragma unroll
    for (int ni = 0; ni < 4; ni++) bv[ni] = bias[n0 + ni * 16 + c0];

    for (int k0 = 0; k0 < FD; k0 += 64) {
        __syncthreads();
        #pragma unroll
        for (int i = 0; i < 4; i++) GLL16(aS[i] + k0, (char*)As + aO[i]);
        #pragma unroll
        for (int i = 0; i < 2; i++) GLL16(bS[i] + k0, (char*)Bs + bO[i]);
        __syncthreads();

        bf16x8 af[2][2];
        #pragma unroll
        for (int mi = 0; mi < 2; mi++)
            #pragma unroll
            for (int kk = 0; kk < 2; kk++) {
                int arow = wid * 32 + mi * 16 + c0;
                int ch = kk * 4 + g;
                af[mi][kk] = *(const bf16x8*)&As[arow * 64 + ((ch ^ (arow & 7)) << 3)];
            }
        bf16x8 bfr[4][2];
        #pragma unroll
        for (int ni = 0; ni < 4; ni++)
            #pragma unroll
            for (int kk = 0; kk < 2; kk++) {
                int brow = ni * 16 + c0;
                int ch = kk * 4 + g;
                bfr[ni][kk] = *(const bf16x8*)&Bs[brow * 64 + ((ch ^ (brow & 7)) << 3)];
            }
        #pragma unroll
        for (int mi = 0; mi < 2; mi++)
            #pragma unroll
            for (int ni = 0; ni < 4; ni++)
                #pragma unroll
                for (int kk = 0; kk < 2; kk++)
                    acc[mi][ni] = __builtin_amdgcn_mfma_f32_16x16x32_bf16(
                        af[mi][kk], bfr[ni][kk], acc[mi][ni], 0, 0, 0);
    }

    #pragma unroll
    for (int mi = 0; mi < 2; mi++)
        #pragma unroll
        for (int r = 0; r < 4; r++) {
            int row = m0 + wid * 32 + mi * 16 + g * 4 + r;
            float* cp = C + (size_t)row * FD + n0;
            #pragma unroll
            for (int ni = 0; ni < 4; ni++)
                cp[ni * 16 + c0] = acc[mi][ni][r] + bv[ni];
        }
}

extern "C" void kernel_launch(void* const* d_in, const int* in_sizes, int n_in,
                              void* d_out, int out_size, void* d_ws, size_t ws_size,
                              hipStream_t stream) {
    const float* x   = (const float*)d_in[0];
    const float* g1  = (const float*)d_in[1];
    const float* be1 = (const float*)d_in[2];
    const float* g2  = (const float*)d_in[3];
    const float* be2 = (const float*)d_in[4];
    const float* wq  = (const float*)d_in[5];
    const float* bq  = (const float*)d_in[6];
    const float* wk  = (const float*)d_in[7];
    const float* bk  = (const float*)d_in[8];
    const float* wv  = (const float*)d_in[9];
    const float* bv  = (const float*)d_in[10];
    const float* wo  = (const float*)d_in[11];
    const float* bo  = (const float*)d_in[12];
    const float* w1  = (const float*)d_in[13];
    const float* b1  = (const float*)d_in[14];
    const float* w2  = (const float*)d_in[15];
    const float* b2  = (const float*)d_in[16];
    const float* wm  = (const float*)d_in[17];
    const float* bm  = (const float*)d_in[18];

    char* wsb = (char*)d_ws;
    bf16_t* qb_   = (bf16_t*)(wsb);                        // 8 MB
    bf16_t* kb_   = (bf16_t*)(wsb + (size_t)8  * 1048576); // 8 MB
    bf16_t* vtb   = (bf16_t*)(wsb + (size_t)16 * 1048576); // 8 MB
    bf16_t* attnb = (bf16_t*)(wsb + (size_t)24 * 1048576); // 8 MB ([B,H,N,DH] bf16)
    bf16_t* out2  = (bf16_t*)(wsb + (size_t)40 * 1048576); // 8 MB (FFN output, merge input)
    bf16_t* wtb   = (bf16_t*)(wsb + (size_t)56 * 1048576); // 2 MB
    bf16_t* w1tb  = (bf16_t*)(wsb + (size_t)58 * 1048576); // 512 KB
    bf16_t* w2tb  = (bf16_t*)(wsb + (size_t)58 * 1048576 + 524288); // 512 KB
    bf16_t* wqtb  = (bf16_t*)(wsb + (size_t)59 * 1048576);            // 128 KB
    bf16_t* wktb  = (bf16_t*)(wsb + (size_t)59 * 1048576 + 131072);   // 128 KB
    bf16_t* wvtb  = (bf16_t*)(wsb + (size_t)59 * 1048576 + 262144);   // 128 KB
    bf16_t* wotb  = (bf16_t*)(wsb + (size_t)59 * 1048576 + 393216);   // 128 KB

    k_prep<<<dim3(400), 256, 0, stream>>>(wm, w1, w2, wq, wk, wv, wo,
                                          wtb, w1tb, w2tb, wqtb, wktb, wvtb, wotb);
    k_ln1_qkv<<<dim3(TOKS / 64, NH), 256, 0, stream>>>(x, g1, be1, wqtb, bq, wktb, bk, wvtb, bv,
                                                       qb_, kb_, vtb);
    k_attn<<<dim3(32, NSEQ / 128), 512, 0, stream>>>(qb_, kb_, vtb, attnb);
    k_pffn<<<dim3(32, 16), 512, 0, stream>>>(attnb, wotb, bo, x, g2, be2,
                                             w1tb, b1, w2tb, b2, out2);
    k_merge<<<dim3(FD / 64, TOKS / 128), 256, 0, stream>>>(out2, wtb, bm, (float*)d_out);
}